// Round 5
// baseline (3997.127 us; speedup 1.0000x reference)
//
#include <hip/hip_runtime.h>
#include <math.h>

// Problem constants
#define BB 4
#define SS 1024
#define DD 2048
#define HH 16
#define DKK 128
#define KKTOP 307           // int(1024 * 0.3)
#define MROWS (BB * SS)     // 4096
static __device__ __constant__ float SCALE = 0.08838834764831845f; // 1/sqrt(128)

// ---------------------------------------------------------------------------
// GEMM: C[M,N] = A[M,K] @ W[N,K]^T + bias[N]   (round-1 verified, unchanged)
// ---------------------------------------------------------------------------
#define TM 128
#define TN 128
#define TK 32
#define LDP (TM + 4)

__global__ __launch_bounds__(256) void gemm_nt_f32(
    const float* __restrict__ A, const float* __restrict__ W,
    const float* __restrict__ bias, float* __restrict__ C,
    int M, int N, int K)
{
    __shared__ float As[TK][LDP];
    __shared__ float Ws[TK][LDP];

    const int tid = threadIdx.x;
    const int bm = blockIdx.x * TM;
    const int bn = blockIdx.y * TN;
    const int tx = tid & 15;
    const int ty = tid >> 4;

    const int lr = tid >> 3;
    const int lk = (tid & 7) << 2;

    float acc[8][8];
    #pragma unroll
    for (int i = 0; i < 8; ++i)
        #pragma unroll
        for (int j = 0; j < 8; ++j) acc[i][j] = 0.f;

    for (int kt = 0; kt < K; kt += TK) {
        __syncthreads();
        const float* Ag = A + (size_t)(bm + lr) * K + kt + lk;
        const float* Wg = W + (size_t)(bn + lr) * K + kt + lk;
        #pragma unroll
        for (int m = 0; m < 4; ++m) {
            float4 av = *(const float4*)(Ag + (size_t)m * 32 * K);
            float4 wv = *(const float4*)(Wg + (size_t)m * 32 * K);
            int r = lr + m * 32;
            As[lk + 0][r] = av.x; As[lk + 1][r] = av.y;
            As[lk + 2][r] = av.z; As[lk + 3][r] = av.w;
            Ws[lk + 0][r] = wv.x; Ws[lk + 1][r] = wv.y;
            Ws[lk + 2][r] = wv.z; Ws[lk + 3][r] = wv.w;
        }
        __syncthreads();

        #pragma unroll
        for (int k = 0; k < TK; ++k) {
            float a[8], w[8];
            *(float4*)&a[0] = *(const float4*)&As[k][ty * 8];
            *(float4*)&a[4] = *(const float4*)&As[k][ty * 8 + 4];
            *(float4*)&w[0] = *(const float4*)&Ws[k][tx * 8];
            *(float4*)&w[4] = *(const float4*)&Ws[k][tx * 8 + 4];
            #pragma unroll
            for (int i = 0; i < 8; ++i)
                #pragma unroll
                for (int j = 0; j < 8; ++j)
                    acc[i][j] += a[i] * w[j];
        }
    }

    float bv[8];
    *(float4*)&bv[0] = *(const float4*)&bias[bn + tx * 8];
    *(float4*)&bv[4] = *(const float4*)&bias[bn + tx * 8 + 4];

    #pragma unroll
    for (int i = 0; i < 8; ++i) {
        float* cp = C + (size_t)(bm + ty * 8 + i) * N + bn + tx * 8;
        float4 o0 = make_float4(acc[i][0] + bv[0], acc[i][1] + bv[1],
                                acc[i][2] + bv[2], acc[i][3] + bv[3]);
        float4 o1 = make_float4(acc[i][4] + bv[4], acc[i][5] + bv[5],
                                acc[i][6] + bv[6], acc[i][7] + bv[7]);
        *(float4*)cp = o0;
        *(float4*)(cp + 4) = o1;
    }
}

// ---------------------------------------------------------------------------
// Fused attn. Block = 32 q-rows of one (b,h); 512 threads = 8 waves.
// Wave wv owns rows 4wv..4wv+3. Lane owns keys {2*lane, 2*lane+1} of each
// 128-key tile -> uv[r][2t+s]. Selection = verified ballot bit-descent.
// K tiles staged half-d with XOR swizzle; XCD-chunked block mapping.
// ---------------------------------------------------------------------------
#define QB 32
#define KTILE 128
#define NKT 8              // SS / KTILE
#define LDQ 132
#define LDW 132
// smem carve (bytes):
//   scores: kts [128][64]f swizzled   @ 0      (32768)
//           qs  [32][132]f            @ 32768  (16896)
//   PV:     wt  [32][132]f            @ 0      (16896)
//           red [256][16]f            @ 16896  (16384)
#define SMEM_BYTES 49664

__device__ __forceinline__ unsigned f2u_ord(float f) {
    unsigned x = __float_as_uint(f);
    return (x & 0x80000000u) ? ~x : (x | 0x80000000u);
}
__device__ __forceinline__ float u2f_ord(unsigned u) {
    return __uint_as_float((u & 0x80000000u) ? (u & 0x7fffffffu) : ~u);
}

__global__ __launch_bounds__(512) void attn_topk_fused(
    const float* __restrict__ Q, const float* __restrict__ Kp,
    const float* __restrict__ V, float* __restrict__ attn_out,
    float* __restrict__ CTX)
{
    __shared__ __align__(16) char smem[SMEM_BYTES];
    float* kts = (float*)smem;             // [128][64] swizzled (scores)
    float* qs  = (float*)(smem + 32768);   // [32][132]          (scores)
    float* wt  = (float*)smem;             // [32][132]          (PV)
    float* red = (float*)(smem + 16896);   // [256][16]          (PV)

    const int tid = threadIdx.x;
    // XCD-chunked bijective block remap: 2048 = 8 XCDs x 256
    const int L = ((int)blockIdx.x & 7) * 256 + ((int)blockIdx.x >> 3);
    const int xb = L & 31;
    const int bh = L >> 5;
    const int h = bh & (HH - 1);
    const int b = bh >> 4;
    const int q0 = xb * QB;

    const int wv = tid >> 6;
    const int lane = tid & 63;

    const float* Qg = Q  + (size_t)(b * SS + q0) * DD + h * DKK;
    const float* Kg = Kp + (size_t)b * SS * DD + h * DKK;
    const float* Vg = V  + (size_t)b * SS * DD + h * DKK;

    // --- stage qs [32][128] padded 132, coalesced ---
    {
        int row = tid >> 4;
        int c0 = tid & 15;
        #pragma unroll
        for (int i = 0; i < 2; ++i) {
            int blk = c0 + 16 * i;
            *(float4*)&qs[row * LDQ + blk * 4] =
                *(const float4*)(Qg + (size_t)row * DD + blk * 4);
        }
    }

    // --- scores: accf[r][2t+s], K tile [128 keys][64 dims] per (t,half) ---
    float accf[4][16];
    #pragma unroll
    for (int r = 0; r < 4; ++r)
        #pragma unroll
        for (int i = 0; i < 16; ++i) accf[r][i] = 0.f;

    for (int t = 0; t < NKT; ++t) {
        #pragma unroll
        for (int dh = 0; dh < 2; ++dh) {
            __syncthreads();   // protect kts (and qs on first iter)
            {
                int row = tid >> 2;          // 0..127
                int bs = (tid & 3) * 4;      // block start within half
                int sw = (row >> 1) & 7;
                #pragma unroll
                for (int i = 0; i < 4; ++i) {
                    float4 kv = *(const float4*)(
                        Kg + (size_t)(t * KTILE + row) * DD + dh * 64 + (bs + i) * 4);
                    int bwz = (bs + i) ^ sw;
                    *(float4*)&kts[row * 64 + bwz * 4] = kv;
                }
            }
            __syncthreads();

            const int sw = lane & 7;
            #pragma unroll
            for (int c = 0; c < 16; ++c) {
                float4 kf0 = *(const float4*)&kts[(2 * lane + 0) * 64 + (c ^ sw) * 4];
                float4 kf1 = *(const float4*)&kts[(2 * lane + 1) * 64 + (c ^ sw) * 4];
                #pragma unroll
                for (int r = 0; r < 4; ++r) {
                    float4 qf = *(const float4*)&qs[(4 * wv + r) * LDQ + (dh * 16 + c) * 4];
                    accf[r][2 * t + 0] += qf.x * kf0.x + qf.y * kf0.y +
                                          qf.z * kf0.z + qf.w * kf0.w;
                    accf[r][2 * t + 1] += qf.x * kf1.x + qf.y * kf1.y +
                                          qf.z * kf1.z + qf.w * kf1.w;
                }
            }
        }
    }

    // --- convert to sortable uints ---
    unsigned uv[4][16];
    #pragma unroll
    for (int r = 0; r < 4; ++r)
        #pragma unroll
        for (int i = 0; i < 16; ++i)
            uv[r][i] = f2u_ord(accf[r][i] * SCALE);

    // --- selection + softmax params per row (verified ballot bit-descent) ---
    unsigned pref[4];
    int ecnt[4];
    float mrow[4], invz[4], tvexp[4];
    #pragma unroll
    for (int r = 0; r < 4; ++r) {
        unsigned p = 0;
        for (int bit = 31; bit >= 0; --bit) {
            unsigned cand = p | (1u << bit);
            int cnt = 0;
            #pragma unroll
            for (int i = 0; i < 16; ++i)
                cnt += __popcll(__ballot(uv[r][i] >= cand));
            if (cnt >= KKTOP) p = cand;
        }
        pref[r] = p;
        int g = 0;
        #pragma unroll
        for (int i = 0; i < 16; ++i)
            g += __popcll(__ballot(uv[r][i] > p));
        ecnt[r] = KKTOP - g;

        unsigned um = 0;
        #pragma unroll
        for (int i = 0; i < 16; ++i) um = um > uv[r][i] ? um : uv[r][i];
        #pragma unroll
        for (int o = 32; o > 0; o >>= 1) {
            unsigned tv2 = __shfl_down(um, o);
            um = um > tv2 ? um : tv2;
        }
        um = __shfl(um, 0);
        const float m = u2f_ord(um);

        float se = 0.f;
        #pragma unroll
        for (int i = 0; i < 16; ++i)
            if (uv[r][i] > p) se += expf(u2f_ord(uv[r][i]) - m);
        #pragma unroll
        for (int o = 32; o > 0; o >>= 1) se += __shfl_down(se, o);
        se = __shfl(se, 0);

        mrow[r] = m;
        tvexp[r] = expf(u2f_ord(p) - m);
        invz[r] = 1.0f / (se + (float)ecnt[r] * tvexp[r]);
    }

    // --- weights in-register + attn write; tie ranks in (t,lane,s) order ---
    #pragma unroll
    for (int r = 0; r < 4; ++r) {
        float* ao = attn_out +
            ((size_t)((b * HH + h) * SS + q0 + 4 * wv + r)) * SS;
        int tb = 0;
        #pragma unroll
        for (int t = 0; t < NKT; ++t) {
            const unsigned u0 = uv[r][2 * t + 0];
            const unsigned u1 = uv[r][2 * t + 1];
            const bool e0 = (u0 == pref[r]);
            const bool e1 = (u1 == pref[r]);
            const unsigned long long m0 = __ballot(e0);
            const unsigned long long m1 = __ballot(e1);
            const unsigned long long below = (1ull << lane) - 1ull;
            const int lowties = __popcll(m0 & below) + __popcll(m1 & below);
            float w0, w1;
            if (u0 > pref[r]) {
                w0 = expf(u2f_ord(u0) - mrow[r]) * invz[r];
            } else if (e0) {
                int rk = tb + lowties;
                w0 = (rk < ecnt[r]) ? tvexp[r] * invz[r] : 0.f;
            } else w0 = 0.f;
            if (u1 > pref[r]) {
                w1 = expf(u2f_ord(u1) - mrow[r]) * invz[r];
            } else if (e1) {
                int rk = tb + lowties + (e0 ? 1 : 0);
                w1 = (rk < ecnt[r]) ? tvexp[r] * invz[r] : 0.f;
            } else w1 = 0.f;
            uv[r][2 * t + 0] = __float_as_uint(w0);
            uv[r][2 * t + 1] = __float_as_uint(w1);
            *(float2*)&ao[t * KTILE + 2 * lane] = make_float2(w0, w1);
            tb += __popcll(m0) + __popcll(m1);
        }
    }

    // --- PV: ctx[32][128] = W[32][1024] @ V[1024][128] ---
    // thread = (ks, rq, dg): rows 4rq..4rq+3, dims 4dg..4dg+3, keys ks-half
    const int ks = tid >> 8;
    const int rq = (tid >> 5) & 7;
    const int dg = tid & 31;
    float a2[4][4];
    #pragma unroll
    for (int r = 0; r < 4; ++r)
        #pragma unroll
        for (int i = 0; i < 4; ++i) a2[r][i] = 0.f;

    const float* Vt = Vg + dg * 4;
    for (int t = 0; t < NKT; ++t) {
        __syncthreads();   // wt region free (scores kts / prev wt reads done)
        #pragma unroll
        for (int r = 0; r < 4; ++r)
            *(float2*)&wt[(4 * wv + r) * LDW + 2 * lane] =
                make_float2(__uint_as_float(uv[r][2 * t + 0]),
                            __uint_as_float(uv[r][2 * t + 1]));
        __syncthreads();

        float4 vnx = *(const float4*)(Vt + (size_t)(t * KTILE + ks * 64) * DD);
        #pragma unroll 4
        for (int jj = 0; jj < 64; ++jj) {
            float4 vc = vnx;
            if (jj < 63)
                vnx = *(const float4*)(Vt + (size_t)(t * KTILE + ks * 64 + jj + 1) * DD);
            const int j = ks * 64 + jj;
            float w0 = wt[(4 * rq + 0) * LDW + j];
            float w1 = wt[(4 * rq + 1) * LDW + j];
            float w2 = wt[(4 * rq + 2) * LDW + j];
            float w3 = wt[(4 * rq + 3) * LDW + j];
            a2[0][0] += w0 * vc.x; a2[0][1] += w0 * vc.y;
            a2[0][2] += w0 * vc.z; a2[0][3] += w0 * vc.w;
            a2[1][0] += w1 * vc.x; a2[1][1] += w1 * vc.y;
            a2[1][2] += w1 * vc.z; a2[1][3] += w1 * vc.w;
            a2[2][0] += w2 * vc.x; a2[2][1] += w2 * vc.y;
            a2[2][2] += w2 * vc.z; a2[2][3] += w2 * vc.w;
            a2[3][0] += w3 * vc.x; a2[3][1] += w3 * vc.y;
            a2[3][2] += w3 * vc.z; a2[3][3] += w3 * vc.w;
        }
    }

    // --- ks reduction + ctx write ---
    __syncthreads();
    if (ks == 1) {
        float* rp = &red[(rq * 32 + dg) * 16];
        #pragma unroll
        for (int r = 0; r < 4; ++r)
            *(float4*)&rp[r * 4] =
                make_float4(a2[r][0], a2[r][1], a2[r][2], a2[r][3]);
    }
    __syncthreads();
    if (ks == 0) {
        const float* rp = &red[(rq * 32 + dg) * 16];
        #pragma unroll
        for (int r = 0; r < 4; ++r) {
            float4 o = *(const float4*)&rp[r * 4];
            float* cb = CTX + (size_t)(b * SS + q0 + 4 * rq + r) * DD + h * DKK + dg * 4;
            *(float4*)cb = make_float4(a2[r][0] + o.x, a2[r][1] + o.y,
                                       a2[r][2] + o.z, a2[r][3] + o.w);
        }
    }
}

// ---------------------------------------------------------------------------
extern "C" void kernel_launch(void* const* d_in, const int* in_sizes, int n_in,
                              void* d_out, int out_size, void* d_ws, size_t ws_size,
                              hipStream_t stream)
{
    const float* x  = (const float*)d_in[0];
    const float* Wq = (const float*)d_in[1];
    const float* bq = (const float*)d_in[2];
    const float* Wk = (const float*)d_in[3];
    const float* bk = (const float*)d_in[4];
    const float* Wv = (const float*)d_in[5];
    const float* bv = (const float*)d_in[6];
    const float* Wo = (const float*)d_in[7];
    const float* bo = (const float*)d_in[8];

    float* out      = (float*)d_out;                       // [4,1024,2048]
    float* attn_out = (float*)d_out + (size_t)MROWS * DD;  // [4,16,1024,1024]

    float* ws = (float*)d_ws;
    const size_t PLANE = (size_t)MROWS * DD;
    float* Qb  = ws;
    float* Kb  = ws + PLANE;
    float* Vb  = ws + 2 * PLANE;
    float* CTX = ws + 3 * PLANE;

    dim3 gb(MROWS / TM, DD / TN);
    gemm_nt_f32<<<gb, 256, 0, stream>>>(x, Wq, bq, Qb, MROWS, DD, DD);
    gemm_nt_f32<<<gb, 256, 0, stream>>>(x, Wk, bk, Kb, MROWS, DD, DD);
    gemm_nt_f32<<<gb, 256, 0, stream>>>(x, Wv, bv, Vb, MROWS, DD, DD);

    attn_topk_fused<<<dim3(MROWS / QB * HH), 512, 0, stream>>>(
        Qb, Kb, Vb, attn_out, CTX);

    gemm_nt_f32<<<gb, 256, 0, stream>>>(CTX, Wo, bo, out, MROWS, DD, DD);
}

// Round 6
// 3001.905 us; speedup vs baseline: 1.3315x; 1.3315x over previous
//
#include <hip/hip_runtime.h>
#include <math.h>

// Problem constants
#define BB 4
#define SS 1024
#define DD 2048
#define HH 16
#define DKK 128
#define KKTOP 307           // int(1024 * 0.3)
#define MROWS (BB * SS)     // 4096
static __device__ __constant__ float SCALE = 0.08838834764831845f; // 1/sqrt(128)

typedef float f32x4 __attribute__((ext_vector_type(4)));
typedef unsigned short su8 __attribute__((ext_vector_type(8)));

// ---------------------------------------------------------------------------
// GEMM fp32: C[M,N] = A[M,K] @ W[N,K]^T + bias[N]  (round-1 verified)
// Used for Q,K projections (feed exact top-k selection).
// ---------------------------------------------------------------------------
#define TM 128
#define TN 128
#define TK 32
#define LDP (TM + 4)

__global__ __launch_bounds__(256) void gemm_nt_f32(
    const float* __restrict__ A, const float* __restrict__ W,
    const float* __restrict__ bias, float* __restrict__ C,
    int M, int N, int K)
{
    __shared__ float As[TK][LDP];
    __shared__ float Ws[TK][LDP];

    const int tid = threadIdx.x;
    const int bm = blockIdx.x * TM;
    const int bn = blockIdx.y * TN;
    const int tx = tid & 15;
    const int ty = tid >> 4;

    const int lr = tid >> 3;
    const int lk = (tid & 7) << 2;

    float acc[8][8];
    #pragma unroll
    for (int i = 0; i < 8; ++i)
        #pragma unroll
        for (int j = 0; j < 8; ++j) acc[i][j] = 0.f;

    for (int kt = 0; kt < K; kt += TK) {
        __syncthreads();
        const float* Ag = A + (size_t)(bm + lr) * K + kt + lk;
        const float* Wg = W + (size_t)(bn + lr) * K + kt + lk;
        #pragma unroll
        for (int m = 0; m < 4; ++m) {
            float4 av = *(const float4*)(Ag + (size_t)m * 32 * K);
            float4 wv = *(const float4*)(Wg + (size_t)m * 32 * K);
            int r = lr + m * 32;
            As[lk + 0][r] = av.x; As[lk + 1][r] = av.y;
            As[lk + 2][r] = av.z; As[lk + 3][r] = av.w;
            Ws[lk + 0][r] = wv.x; Ws[lk + 1][r] = wv.y;
            Ws[lk + 2][r] = wv.z; Ws[lk + 3][r] = wv.w;
        }
        __syncthreads();

        #pragma unroll
        for (int k = 0; k < TK; ++k) {
            float a[8], w[8];
            *(float4*)&a[0] = *(const float4*)&As[k][ty * 8];
            *(float4*)&a[4] = *(const float4*)&As[k][ty * 8 + 4];
            *(float4*)&w[0] = *(const float4*)&Ws[k][tx * 8];
            *(float4*)&w[4] = *(const float4*)&Ws[k][tx * 8 + 4];
            #pragma unroll
            for (int i = 0; i < 8; ++i)
                #pragma unroll
                for (int j = 0; j < 8; ++j)
                    acc[i][j] += a[i] * w[j];
        }
    }

    float bv[8];
    *(float4*)&bv[0] = *(const float4*)&bias[bn + tx * 8];
    *(float4*)&bv[4] = *(const float4*)&bias[bn + tx * 8 + 4];

    #pragma unroll
    for (int i = 0; i < 8; ++i) {
        float* cp = C + (size_t)(bm + ty * 8 + i) * N + bn + tx * 8;
        float4 o0 = make_float4(acc[i][0] + bv[0], acc[i][1] + bv[1],
                                acc[i][2] + bv[2], acc[i][3] + bv[3]);
        float4 o1 = make_float4(acc[i][4] + bv[4], acc[i][5] + bv[5],
                                acc[i][6] + bv[6], acc[i][7] + bv[7]);
        *(float4*)cp = o0;
        *(float4*)(cp + 4) = o1;
    }
}

// ---------------------------------------------------------------------------
// GEMM bf16-MFMA: C[M,N] = A[M,K] @ W[N,K]^T + bias[N], fp32 in/out,
// inputs rounded to bf16 (RNE) during LDS staging, fp32 MFMA accumulate.
// 128x128 tile, BK=32, 256 threads = 4 waves (2x2), wave = 64x64 out
// = 4x4 frags of v_mfma_f32_16x16x32_bf16 (inline asm).
// A-frag: lane holds A[m0+(l&15)][k0 + (l>>4)*8 .. +7]
// B-frag: lane holds W[n0+(l&15)][k0 + (l>>4)*8 .. +7]   (B = W^T)
// D-frag: row = m0+(l>>4)*4+j, col = n0+(l&15)           (guide §3, m89)
// ---------------------------------------------------------------------------
#define GLDA 40   // LDS row stride in bf16 units (80 B)

__device__ __forceinline__ unsigned short f2bf(float x) {   // RNE
    unsigned u = __float_as_uint(x);
    u += 0x7fffu + ((u >> 16) & 1u);
    return (unsigned short)(u >> 16);
}
__device__ __forceinline__ su8 pack8(float4 x, float4 y) {
    su8 r;
    r[0] = f2bf(x.x); r[1] = f2bf(x.y); r[2] = f2bf(x.z); r[3] = f2bf(x.w);
    r[4] = f2bf(y.x); r[5] = f2bf(y.y); r[6] = f2bf(y.z); r[7] = f2bf(y.w);
    return r;
}

__global__ __launch_bounds__(256) void gemm_nt_bf16(
    const float* __restrict__ A, const float* __restrict__ W,
    const float* __restrict__ bias, float* __restrict__ C,
    int M, int N, int K)
{
    __shared__ unsigned short Ab[128][GLDA];
    __shared__ unsigned short Bb[128][GLDA];

    const int tid = threadIdx.x;
    const int bm = blockIdx.x * 128;
    const int bn = blockIdx.y * 128;
    const int wm = (tid >> 6) & 1;   // wave row
    const int wn = tid >> 7;         // wave col
    const int lane = tid & 63;
    const int lrow = tid >> 1;       // staging: 0..127
    const int lcol = (tid & 1) * 16; // staging: 0 or 16

    f32x4 acc[4][4];
    #pragma unroll
    for (int i = 0; i < 4; ++i)
        #pragma unroll
        for (int j = 0; j < 4; ++j)
            acc[i][j] = (f32x4){0.f, 0.f, 0.f, 0.f};

    for (int kt = 0; kt < K; kt += 32) {
        __syncthreads();
        {
            const float* Ag = A + (size_t)(bm + lrow) * K + kt + lcol;
            const float* Wg = W + (size_t)(bn + lrow) * K + kt + lcol;
            float4 a0 = *(const float4*)(Ag + 0);
            float4 a1 = *(const float4*)(Ag + 4);
            float4 a2 = *(const float4*)(Ag + 8);
            float4 a3 = *(const float4*)(Ag + 12);
            *(su8*)&Ab[lrow][lcol + 0] = pack8(a0, a1);
            *(su8*)&Ab[lrow][lcol + 8] = pack8(a2, a3);
            float4 b0 = *(const float4*)(Wg + 0);
            float4 b1 = *(const float4*)(Wg + 4);
            float4 b2 = *(const float4*)(Wg + 8);
            float4 b3 = *(const float4*)(Wg + 12);
            *(su8*)&Bb[lrow][lcol + 0] = pack8(b0, b1);
            *(su8*)&Bb[lrow][lcol + 8] = pack8(b2, b3);
        }
        __syncthreads();

        su8 af[4], bf[4];
        #pragma unroll
        for (int f = 0; f < 4; ++f) {
            af[f] = *(const su8*)&Ab[wm * 64 + f * 16 + (lane & 15)][(lane >> 4) * 8];
            bf[f] = *(const su8*)&Bb[wn * 64 + f * 16 + (lane & 15)][(lane >> 4) * 8];
        }
        #pragma unroll
        for (int fi = 0; fi < 4; ++fi)
            #pragma unroll
            for (int fj = 0; fj < 4; ++fj)
                asm volatile("v_mfma_f32_16x16x32_bf16 %0, %1, %2, %0"
                             : "+v"(acc[fi][fj])
                             : "v"(af[fi]), "v"(bf[fj]));
    }

    asm volatile("s_nop 7\n\ts_nop 7" ::: "memory");  // drain MFMA latency

    #pragma unroll
    for (int fj = 0; fj < 4; ++fj) {
        const int col = bn + wn * 64 + fj * 16 + (lane & 15);
        const float bv = bias[col];
        #pragma unroll
        for (int fi = 0; fi < 4; ++fi) {
            const int r0 = bm + wm * 64 + fi * 16 + (lane >> 4) * 4;
            #pragma unroll
            for (int j = 0; j < 4; ++j)
                C[(size_t)(r0 + j) * N + col] = acc[fi][fj][j] + bv;
        }
    }
}

// ---------------------------------------------------------------------------
// Fused attn — EXACT round-4 kernel (measured 2050 us, conflict-free),
// only change: XCD-chunked bijective 1D block remap (round-5-verified
// FETCH 640->218 MB). Block = 32 q-rows of one (b,h); 512 thr = 8 waves.
// ---------------------------------------------------------------------------
#define QB 32
#define KT2 64
#define NT 16              // SS / KT2
#define LDQ 132            // padded row stride (floats)
#define QS_OFF 0
#define KT_OFF (QB * LDQ)
#define LDS_FLOATS (KT_OFF + KT2 * LDQ)   // 12672 floats = 50688 B

__device__ __forceinline__ unsigned f2u_ord(float f) {
    unsigned x = __float_as_uint(f);
    return (x & 0x80000000u) ? ~x : (x | 0x80000000u);
}
__device__ __forceinline__ float u2f_ord(unsigned u) {
    return __uint_as_float((u & 0x80000000u) ? (u & 0x7fffffffu) : ~u);
}

__global__ __launch_bounds__(512) void attn_topk_fused(
    const float* __restrict__ Q, const float* __restrict__ Kp,
    const float* __restrict__ V, float* __restrict__ attn_out,
    float* __restrict__ CTX)
{
    __shared__ float lds[LDS_FLOATS];
    float* qs = lds + QS_OFF;
    float* kt = lds + KT_OFF;

    const int tid = threadIdx.x;
    // XCD-chunked bijective remap: 2048 = 8 XCDs x 256; each XCD gets
    // 8 contiguous (b,h) planes -> K/V L2-resident per XCD.
    const int L = ((int)blockIdx.x & 7) * 256 + ((int)blockIdx.x >> 3);
    const int xb = L & 31;
    const int bh = L >> 5;
    const int h = bh & (HH - 1);
    const int b = bh >> 4;
    const int q0 = xb * QB;

    const int wv = tid >> 6;
    const int lane = tid & 63;

    // --- stage Q tile [32][128] padded 132, coalesced ---
    {
        const float* Qg = Q + (size_t)(b * SS + q0) * DD + h * DKK;
        #pragma unroll
        for (int it = 0; it < 2; ++it) {
            int r = it * 16 + (tid >> 5);
            int c = (tid & 31) * 4;
            *(float4*)&qs[r * LDQ + c] = *(const float4*)(Qg + (size_t)r * DD + c);
        }
    }

    unsigned uv[4][NT];    // wave's 4 rows x 16 tiles (key = t*64 + lane)

    // --- scores: tiled over keys, K-tile in LDS ---
    {
        const float* Kg = Kp + (size_t)b * SS * DD + h * DKK;
        for (int t = 0; t < NT; ++t) {
            __syncthreads();   // prev tile's compute done (and Q stage for t=0)
            #pragma unroll
            for (int it = 0; it < 4; ++it) {
                int r = it * 16 + (tid >> 5);
                int c = (tid & 31) * 4;
                *(float4*)&kt[r * LDQ + c] =
                    *(const float4*)(Kg + (size_t)(t * KT2 + r) * DD + c);
            }
            __syncthreads();

            float a0 = 0.f, a1 = 0.f, a2 = 0.f, a3 = 0.f;
            const float* kr = &kt[lane * LDQ];
            const float* qp0 = &qs[(4 * wv + 0) * LDQ];
            const float* qp1 = &qs[(4 * wv + 1) * LDQ];
            const float* qp2 = &qs[(4 * wv + 2) * LDQ];
            const float* qp3 = &qs[(4 * wv + 3) * LDQ];
            #pragma unroll 8
            for (int d = 0; d < DKK; d += 4) {
                float4 kf = *(const float4*)(kr + d);
                float4 f0 = *(const float4*)(qp0 + d);
                float4 f1 = *(const float4*)(qp1 + d);
                float4 f2 = *(const float4*)(qp2 + d);
                float4 f3 = *(const float4*)(qp3 + d);
                a0 += f0.x * kf.x + f0.y * kf.y + f0.z * kf.z + f0.w * kf.w;
                a1 += f1.x * kf.x + f1.y * kf.y + f1.z * kf.z + f1.w * kf.w;
                a2 += f2.x * kf.x + f2.y * kf.y + f2.z * kf.z + f2.w * kf.w;
                a3 += f3.x * kf.x + f3.y * kf.y + f3.z * kf.z + f3.w * kf.w;
            }
            uv[0][t] = f2u_ord(a0 * SCALE);
            uv[1][t] = f2u_ord(a1 * SCALE);
            uv[2][t] = f2u_ord(a2 * SCALE);
            uv[3][t] = f2u_ord(a3 * SCALE);
        }
    }

    // --- selection + softmax params per row (verified ballot bit-descent) ---
    unsigned pref[4];
    int ecnt[4];
    float mrow[4], invz[4], tvexp[4];
    #pragma unroll
    for (int r = 0; r < 4; ++r) {
        unsigned p = 0;
        for (int bit = 31; bit >= 0; --bit) {
            unsigned cand = p | (1u << bit);
            int cnt = 0;
            #pragma unroll
            for (int t = 0; t < NT; ++t)
                cnt += __popcll(__ballot(uv[r][t] >= cand));
            if (cnt >= KKTOP) p = cand;
        }
        pref[r] = p;
        int g = 0;
        #pragma unroll
        for (int t = 0; t < NT; ++t)
            g += __popcll(__ballot(uv[r][t] > p));
        ecnt[r] = KKTOP - g;

        unsigned um = 0;
        #pragma unroll
        for (int t = 0; t < NT; ++t) um = um > uv[r][t] ? um : uv[r][t];
        #pragma unroll
        for (int o = 32; o > 0; o >>= 1) {
            unsigned tv2 = __shfl_down(um, o);
            um = um > tv2 ? um : tv2;
        }
        um = __shfl(um, 0);
        const float m = u2f_ord(um);

        float se = 0.f;
        #pragma unroll
        for (int t = 0; t < NT; ++t)
            if (uv[r][t] > p) se += expf(u2f_ord(uv[r][t]) - m);
        #pragma unroll
        for (int o = 32; o > 0; o >>= 1) se += __shfl_down(se, o);
        se = __shfl(se, 0);

        mrow[r] = m;
        tvexp[r] = expf(u2f_ord(p) - m);
        invz[r] = 1.0f / (se + (float)ecnt[r] * tvexp[r]);
    }

    // --- weights (in-register) + attn write; ties in (t,lane) index order ---
    #pragma unroll
    for (int r = 0; r < 4; ++r) {
        float* ao = attn_out +
            ((size_t)((b * HH + h) * SS + q0 + 4 * wv + r)) * SS;
        int tiesbefore = 0;
        #pragma unroll
        for (int t = 0; t < NT; ++t) {
            const unsigned u = uv[r][t];
            const bool eq = (u == pref[r]);
            unsigned long long mask = __ballot(eq);
            float w;
            if (u > pref[r]) {
                w = expf(u2f_ord(u) - mrow[r]) * invz[r];
            } else if (eq) {
                int rank = tiesbefore + __popcll(mask & ((1ull << lane) - 1ull));
                w = (rank < ecnt[r]) ? tvexp[r] * invz[r] : 0.f;
            } else {
                w = 0.f;
            }
            uv[r][t] = __float_as_uint(w);
            ao[t * 64 + lane] = w;
            tiesbefore += __popcll(mask);
        }
    }

    // --- PV: ctx[32][128] = W[32][1024] @ V[1024][128], tiled ---
    float* wt = lds + QS_OFF;   // wtile [32][64]  (qs dead)
    float* vt = lds + KT_OFF;   // vtile [64][132]
    const int d = tid & 127;
    const int rq = tid >> 7;    // rows rq*8 .. rq*8+7
    float acc2[8];
    #pragma unroll
    for (int i = 0; i < 8; ++i) acc2[i] = 0.f;

    const float* Vg = V + (size_t)b * SS * DD + h * DKK;
    for (int t = 0; t < NT; ++t) {
        __syncthreads();
        #pragma unroll
        for (int it = 0; it < 4; ++it) {
            int r = it * 16 + (tid >> 5);
            int c = (tid & 31) * 4;
            *(float4*)&vt[r * LDQ + c] =
                *(const float4*)(Vg + (size_t)(t * KT2 + r) * DD + c);
        }
        #pragma unroll
        for (int r = 0; r < 4; ++r)
            wt[(4 * wv + r) * 64 + lane] = __uint_as_float(uv[r][t]);
        __syncthreads();

        #pragma unroll 4
        for (int jg = 0; jg < KT2; jg += 4) {
            float4 wrow[8];
            #pragma unroll
            for (int i = 0; i < 8; ++i)
                wrow[i] = *(const float4*)&wt[(rq * 8 + i) * 64 + jg];
            float v0 = vt[(jg + 0) * LDQ + d];
            float v1 = vt[(jg + 1) * LDQ + d];
            float v2 = vt[(jg + 2) * LDQ + d];
            float v3 = vt[(jg + 3) * LDQ + d];
            #pragma unroll
            for (int i = 0; i < 8; ++i)
                acc2[i] += wrow[i].x * v0 + wrow[i].y * v1 +
                           wrow[i].z * v2 + wrow[i].w * v3;
        }
    }

    {
        float* cb = CTX + (size_t)(b * SS + q0 + rq * 8) * DD + h * DKK + d;
        #pragma unroll
        for (int i = 0; i < 8; ++i)
            cb[(size_t)i * DD] = acc2[i];
    }
}

// ---------------------------------------------------------------------------
extern "C" void kernel_launch(void* const* d_in, const int* in_sizes, int n_in,
                              void* d_out, int out_size, void* d_ws, size_t ws_size,
                              hipStream_t stream)
{
    const float* x  = (const float*)d_in[0];
    const float* Wq = (const float*)d_in[1];
    const float* bq = (const float*)d_in[2];
    const float* Wk = (const float*)d_in[3];
    const float* bk = (const float*)d_in[4];
    const float* Wv = (const float*)d_in[5];
    const float* bv = (const float*)d_in[6];
    const float* Wo = (const float*)d_in[7];
    const float* bo = (const float*)d_in[8];

    float* out      = (float*)d_out;                       // [4,1024,2048]
    float* attn_out = (float*)d_out + (size_t)MROWS * DD;  // [4,16,1024,1024]

    float* ws = (float*)d_ws;
    const size_t PLANE = (size_t)MROWS * DD;
    float* Qb  = ws;
    float* Kb  = ws + PLANE;
    float* Vb  = ws + 2 * PLANE;
    float* CTX = ws + 3 * PLANE;

    dim3 gb(MROWS / TM, DD / TN);   // (32,16)
    gemm_nt_f32 <<<gb, 256, 0, stream>>>(x, Wq, bq, Qb, MROWS, DD, DD);
    gemm_nt_f32 <<<gb, 256, 0, stream>>>(x, Wk, bk, Kb, MROWS, DD, DD);
    gemm_nt_bf16<<<gb, 256, 0, stream>>>(x, Wv, bv, Vb, MROWS, DD, DD);

    attn_topk_fused<<<dim3(MROWS / QB * HH), 512, 0, stream>>>(
        Qb, Kb, Vb, attn_out, CTX);

    gemm_nt_bf16<<<gb, 256, 0, stream>>>(CTX, Wo, bo, out, MROWS, DD, DD);
}

// Round 8
// 1710.024 us; speedup vs baseline: 2.3375x; 1.7555x over previous
//
#include <hip/hip_runtime.h>
#include <math.h>

// Problem constants
#define BB 4
#define SS 1024
#define DD 2048
#define HH 16
#define DKK 128
#define KKTOP 307           // int(1024 * 0.3)
#define MROWS (BB * SS)     // 4096
static __device__ __constant__ float SCALE = 0.08838834764831845f; // 1/sqrt(128)

typedef float f32x4 __attribute__((ext_vector_type(4)));
typedef unsigned short su4 __attribute__((ext_vector_type(4)));
typedef unsigned short su8 __attribute__((ext_vector_type(8)));

__device__ __forceinline__ unsigned short f2bf(float x) {   // RNE
    unsigned u = __float_as_uint(x);
    u += 0x7fffu + ((u >> 16) & 1u);
    return (unsigned short)(u >> 16);
}
__device__ __forceinline__ float bf2f(unsigned short b) {
    return __uint_as_float((unsigned)b << 16);
}
__device__ __forceinline__ unsigned f2u_ord(float f) {
    unsigned x = __float_as_uint(f);
    return (x & 0x80000000u) ? ~x : (x | 0x80000000u);
}
__device__ __forceinline__ float u2f_ord(unsigned u) {
    return __uint_as_float((u & 0x80000000u) ? (u & 0x7fffffffu) : ~u);
}
// 3-way bf16 split of fp32 (captures ~24 mantissa bits)
__device__ __forceinline__ void split4(float4 v, su4& a, su4& b, su4& c) {
    float x[4] = {v.x, v.y, v.z, v.w};
    #pragma unroll
    for (int i = 0; i < 4; ++i) {
        unsigned short b1 = f2bf(x[i]);
        float r = x[i] - bf2f(b1);
        unsigned short b2 = f2bf(r);
        float r2 = r - bf2f(b2);
        a[i] = b1; b[i] = b2; c[i] = f2bf(r2);
    }
}

// ---------------------------------------------------------------------------
// GEMM fp32 (round-1 verified, verbatim): Q,K projections.
// ---------------------------------------------------------------------------
#define TM 128
#define TN 128
#define TK 32
#define LDP (TM + 4)

__global__ __launch_bounds__(256) void gemm_nt_f32(
    const float* __restrict__ A, const float* __restrict__ W,
    const float* __restrict__ bias, float* __restrict__ C,
    int M, int N, int K)
{
    __shared__ float As[TK][LDP];
    __shared__ float Ws[TK][LDP];

    const int tid = threadIdx.x;
    const int bm = blockIdx.x * TM;
    const int bn = blockIdx.y * TN;
    const int tx = tid & 15;
    const int ty = tid >> 4;
    const int lr = tid >> 3;
    const int lk = (tid & 7) << 2;

    float acc[8][8];
    #pragma unroll
    for (int i = 0; i < 8; ++i)
        #pragma unroll
        for (int j = 0; j < 8; ++j) acc[i][j] = 0.f;

    for (int kt = 0; kt < K; kt += TK) {
        __syncthreads();
        const float* Ag = A + (size_t)(bm + lr) * K + kt + lk;
        const float* Wg = W + (size_t)(bn + lr) * K + kt + lk;
        #pragma unroll
        for (int m = 0; m < 4; ++m) {
            float4 av = *(const float4*)(Ag + (size_t)m * 32 * K);
            float4 wv = *(const float4*)(Wg + (size_t)m * 32 * K);
            int r = lr + m * 32;
            As[lk + 0][r] = av.x; As[lk + 1][r] = av.y;
            As[lk + 2][r] = av.z; As[lk + 3][r] = av.w;
            Ws[lk + 0][r] = wv.x; Ws[lk + 1][r] = wv.y;
            Ws[lk + 2][r] = wv.z; Ws[lk + 3][r] = wv.w;
        }
        __syncthreads();

        #pragma unroll
        for (int k = 0; k < TK; ++k) {
            float a[8], w[8];
            *(float4*)&a[0] = *(const float4*)&As[k][ty * 8];
            *(float4*)&a[4] = *(const float4*)&As[k][ty * 8 + 4];
            *(float4*)&w[0] = *(const float4*)&Ws[k][tx * 8];
            *(float4*)&w[4] = *(const float4*)&Ws[k][tx * 8 + 4];
            #pragma unroll
            for (int i = 0; i < 8; ++i)
                #pragma unroll
                for (int j = 0; j < 8; ++j)
                    acc[i][j] += a[i] * w[j];
        }
    }

    float bv[8];
    *(float4*)&bv[0] = *(const float4*)&bias[bn + tx * 8];
    *(float4*)&bv[4] = *(const float4*)&bias[bn + tx * 8 + 4];

    #pragma unroll
    for (int i = 0; i < 8; ++i) {
        float* cp = C + (size_t)(bm + ty * 8 + i) * N + bn + tx * 8;
        float4 o0 = make_float4(acc[i][0] + bv[0], acc[i][1] + bv[1],
                                acc[i][2] + bv[2], acc[i][3] + bv[3]);
        float4 o1 = make_float4(acc[i][4] + bv[4], acc[i][5] + bv[5],
                                acc[i][6] + bv[6], acc[i][7] + bv[7]);
        *(float4*)cp = o0;
        *(float4*)(cp + 4) = o1;
    }
}

// ---------------------------------------------------------------------------
// GEMM bf16-MFMA (round-6 verified, verbatim): fp32 in/out. Used for O-proj.
// ---------------------------------------------------------------------------
#define GLDA 40

__device__ __forceinline__ su8 pack8(float4 x, float4 y) {
    su8 r;
    r[0] = f2bf(x.x); r[1] = f2bf(x.y); r[2] = f2bf(x.z); r[3] = f2bf(x.w);
    r[4] = f2bf(y.x); r[5] = f2bf(y.y); r[6] = f2bf(y.z); r[7] = f2bf(y.w);
    return r;
}

__global__ __launch_bounds__(256) void gemm_nt_bf16(
    const float* __restrict__ A, const float* __restrict__ W,
    const float* __restrict__ bias, float* __restrict__ C,
    int M, int N, int K)
{
    __shared__ unsigned short Ab[128][GLDA];
    __shared__ unsigned short Bb[128][GLDA];

    const int tid = threadIdx.x;
    const int bm = blockIdx.x * 128;
    const int bn = blockIdx.y * 128;
    const int wm = (tid >> 6) & 1;
    const int wn = tid >> 7;
    const int lane = tid & 63;
    const int lrow = tid >> 1;
    const int lcol = (tid & 1) * 16;

    f32x4 acc[4][4];
    #pragma unroll
    for (int i = 0; i < 4; ++i)
        #pragma unroll
        for (int j = 0; j < 4; ++j)
            acc[i][j] = (f32x4){0.f, 0.f, 0.f, 0.f};

    for (int kt = 0; kt < K; kt += 32) {
        __syncthreads();
        {
            const float* Ag = A + (size_t)(bm + lrow) * K + kt + lcol;
            const float* Wg = W + (size_t)(bn + lrow) * K + kt + lcol;
            float4 a0 = *(const float4*)(Ag + 0);
            float4 a1 = *(const float4*)(Ag + 4);
            float4 a2 = *(const float4*)(Ag + 8);
            float4 a3 = *(const float4*)(Ag + 12);
            *(su8*)&Ab[lrow][lcol + 0] = pack8(a0, a1);
            *(su8*)&Ab[lrow][lcol + 8] = pack8(a2, a3);
            float4 b0 = *(const float4*)(Wg + 0);
            float4 b1 = *(const float4*)(Wg + 4);
            float4 b2 = *(const float4*)(Wg + 8);
            float4 b3 = *(const float4*)(Wg + 12);
            *(su8*)&Bb[lrow][lcol + 0] = pack8(b0, b1);
            *(su8*)&Bb[lrow][lcol + 8] = pack8(b2, b3);
        }
        __syncthreads();

        su8 af[4], bf[4];
        #pragma unroll
        for (int f = 0; f < 4; ++f) {
            af[f] = *(const su8*)&Ab[wm * 64 + f * 16 + (lane & 15)][(lane >> 4) * 8];
            bf[f] = *(const su8*)&Bb[wn * 64 + f * 16 + (lane & 15)][(lane >> 4) * 8];
        }
        #pragma unroll
        for (int fi = 0; fi < 4; ++fi)
            #pragma unroll
            for (int fj = 0; fj < 4; ++fj)
                asm volatile("v_mfma_f32_16x16x32_bf16 %0, %1, %2, %0"
                             : "+v"(acc[fi][fj])
                             : "v"(af[fi]), "v"(bf[fj]));
    }

    asm volatile("s_nop 7\n\ts_nop 7" ::: "memory");

    #pragma unroll
    for (int fj = 0; fj < 4; ++fj) {
        const int col = bn + wn * 64 + fj * 16 + (lane & 15);
        const float bv = bias[col];
        #pragma unroll
        for (int fi = 0; fi < 4; ++fi) {
            const int r0 = bm + wm * 64 + fi * 16 + (lane >> 4) * 4;
            #pragma unroll
            for (int j = 0; j < 4; ++j)
                C[(size_t)(r0 + j) * N + col] = acc[fi][fj][j] + bv;
        }
    }
}

// ---------------------------------------------------------------------------
// GEMM bf16-MFMA, transposed-V variant: C[M=vdim][N=token] = A@W^T + bias[row],
// bf16 OUTPUT. A=Wv [2048][2048], W=x [4096][2048] -> Vt[vdim][token].
// ---------------------------------------------------------------------------
__global__ __launch_bounds__(256) void gemm_nt_bf16_tv(
    const float* __restrict__ A, const float* __restrict__ W,
    const float* __restrict__ bias, unsigned short* __restrict__ Cb,
    int M, int N, int K)
{
    __shared__ unsigned short Ab[128][GLDA];
    __shared__ unsigned short Bb[128][GLDA];

    const int tid = threadIdx.x;
    const int bm = blockIdx.x * 128;
    const int bn = blockIdx.y * 128;
    const int wm = (tid >> 6) & 1;
    const int wn = tid >> 7;
    const int lane = tid & 63;
    const int lrow = tid >> 1;
    const int lcol = (tid & 1) * 16;

    f32x4 acc[4][4];
    #pragma unroll
    for (int i = 0; i < 4; ++i)
        #pragma unroll
        for (int j = 0; j < 4; ++j)
            acc[i][j] = (f32x4){0.f, 0.f, 0.f, 0.f};

    for (int kt = 0; kt < K; kt += 32) {
        __syncthreads();
        {
            const float* Ag = A + (size_t)(bm + lrow) * K + kt + lcol;
            const float* Wg = W + (size_t)(bn + lrow) * K + kt + lcol;
            float4 a0 = *(const float4*)(Ag + 0);
            float4 a1 = *(const float4*)(Ag + 4);
            float4 a2 = *(const float4*)(Ag + 8);
            float4 a3 = *(const float4*)(Ag + 12);
            *(su8*)&Ab[lrow][lcol + 0] = pack8(a0, a1);
            *(su8*)&Ab[lrow][lcol + 8] = pack8(a2, a3);
            float4 b0 = *(const float4*)(Wg + 0);
            float4 b1 = *(const float4*)(Wg + 4);
            float4 b2 = *(const float4*)(Wg + 8);
            float4 b3 = *(const float4*)(Wg + 12);
            *(su8*)&Bb[lrow][lcol + 0] = pack8(b0, b1);
            *(su8*)&Bb[lrow][lcol + 8] = pack8(b2, b3);
        }
        __syncthreads();

        su8 af[4], bf[4];
        #pragma unroll
        for (int f = 0; f < 4; ++f) {
            af[f] = *(const su8*)&Ab[wm * 64 + f * 16 + (lane & 15)][(lane >> 4) * 8];
            bf[f] = *(const su8*)&Bb[wn * 64 + f * 16 + (lane & 15)][(lane >> 4) * 8];
        }
        #pragma unroll
        for (int fi = 0; fi < 4; ++fi)
            #pragma unroll
            for (int fj = 0; fj < 4; ++fj)
                asm volatile("v_mfma_f32_16x16x32_bf16 %0, %1, %2, %0"
                             : "+v"(acc[fi][fj])
                             : "v"(af[fi]), "v"(bf[fj]));
    }

    asm volatile("s_nop 7\n\ts_nop 7" ::: "memory");

    #pragma unroll
    for (int fj = 0; fj < 4; ++fj) {
        const int col = bn + wn * 64 + fj * 16 + (lane & 15);
        #pragma unroll
        for (int fi = 0; fi < 4; ++fi) {
            const int r0 = bm + wm * 64 + fi * 16 + (lane >> 4) * 4;
            #pragma unroll
            for (int j = 0; j < 4; ++j) {
                float v = acc[fi][fj][j] + bias[r0 + j];
                Cb[(size_t)(r0 + j) * N + col] = f2bf(v);
            }
        }
    }
}

// ---------------------------------------------------------------------------
// Fused attn, MFMA scores (3-way bf16 split, 6 passes) + MFMA PV.
// Block = 16 q-rows of one (b,h); 4096 blocks; 512 thr = 8 waves.
// Waves: (ntile = wv&3) x (d-half = wv>>2); partial-sums reduced via LDS.
// Scores (fp32, scaled) round-trip through attn_out (row-private scratch).
// Selection = verified ballot bit-descent (2 rows per wave), verbatim.
// ---------------------------------------------------------------------------
#define ATT_LDS 65280

__global__ __launch_bounds__(512) void attn_topk_fused(
    const float* __restrict__ Qb, const float* __restrict__ Kb,
    const unsigned short* __restrict__ Vt, float* __restrict__ attn_out,
    float* __restrict__ CTX)
{
    __shared__ __align__(16) char smem[ATT_LDS];
    unsigned short* q_s = (unsigned short*)smem;                   // [3][16][136]
    unsigned short* k_s = (unsigned short*)(smem + 13056);         // [3][64][136]
    float*          red = (float*)smem;                            // [4][16][16]
    unsigned short* wt  = (unsigned short*)(smem + 13056);         // [16][1032]
    unsigned short* vt  = (unsigned short*)(smem + 13056 + 33024); // [128][72]

    const int tid = threadIdx.x;
    const int wv = tid >> 6, lane = tid & 63;
    const int fg = lane >> 4, fc = lane & 15;

    // XCD-chunked bijective remap: 4096 = 8 XCDs x 512
    const int gg = (blockIdx.x & 7) * 512 + ((int)blockIdx.x >> 3);
    const int bh = gg >> 6, qb = gg & 63;
    const int b = bh >> 4, h = bh & 15;
    const int q0 = qb * 16;

    const float* Qg = Qb + (size_t)(b * SS + q0) * DD + h * DKK;
    const float* Kg = Kb + (size_t)(b * SS) * DD + h * DKK;
    const unsigned short* Vtg = Vt + (size_t)(h * DKK) * MROWS + b * SS;
    float* aob = attn_out + (size_t)(bh * SS + q0) * SS;

    // ---- stage Q splits (once): 512 units = 16 rows x 32 c4 ----
    {
        int row = tid >> 5, c4 = tid & 31;
        float4 v = *(const float4*)(Qg + (size_t)row * DD + c4 * 4);
        int off = row * 136 + (((c4 >> 1) ^ (row & 7)) * 8) + (c4 & 1) * 4;
        su4 p1, p2, p3; split4(v, p1, p2, p3);
        *(su4*)&q_s[off] = p1;
        *(su4*)&q_s[2176 + off] = p2;
        *(su4*)&q_s[4352 + off] = p3;
    }
    __syncthreads();

    // ---- persistent A-frags: af[split][ktile-of-my-dhalf] ----
    const int kt0 = (wv >> 2) * 2;   // ktile base: 0 (d 0..63) or 2 (d 64..127)
    su8 af[3][2];
    #pragma unroll
    for (int p = 0; p < 3; ++p)
        #pragma unroll
        for (int kk = 0; kk < 2; ++kk)
            af[p][kk] = *(const su8*)&q_s[p * 2176 + fc * 136 +
                            ((((kt0 + kk) * 4 + fg) ^ (fc & 7)) * 8)];

    // ---- scores over 16 key-tiles of 64 ----
    for (int t = 0; t < 16; ++t) {
        #pragma unroll
        for (int u = 0; u < 4; ++u) {
            int rem = tid + 512 * u;
            int row = rem >> 5, c4 = rem & 31;
            float4 v = *(const float4*)(Kg + (size_t)(t * 64 + row) * DD + c4 * 4);
            int off = row * 136 + (((c4 >> 1) ^ (row & 7)) * 8) + (c4 & 1) * 4;
            su4 p1, p2, p3; split4(v, p1, p2, p3);
            *(su4*)&k_s[off] = p1;
            *(su4*)&k_s[8704 + off] = p2;
            *(su4*)&k_s[17408 + off] = p3;
        }
        __syncthreads();

        const int krow = (wv & 3) * 16 + fc;
        su8 bf[3][2];
        #pragma unroll
        for (int p = 0; p < 3; ++p)
            #pragma unroll
            for (int kk = 0; kk < 2; ++kk)
                bf[p][kk] = *(const su8*)&k_s[p * 8704 + krow * 136 +
                                ((((kt0 + kk) * 4 + fg) ^ (krow & 7)) * 8)];

        f32x4 acc = {0.f, 0.f, 0.f, 0.f};
        // passes small->large: (q3,k1),(q1,k3),(q2,k2),(q2,k1),(q1,k2),(q1,k1)
        constexpr int PI[6] = {2, 0, 1, 1, 0, 0};
        constexpr int PJ[6] = {0, 2, 1, 0, 1, 0};
        #pragma unroll
        for (int p = 0; p < 6; ++p)
            #pragma unroll
            for (int kk = 0; kk < 2; ++kk)
                asm volatile("v_mfma_f32_16x16x32_bf16 %0, %1, %2, %0"
                             : "+v"(acc) : "v"(af[PI[p]][kk]), "v"(bf[PJ[p]][kk]));
        asm volatile("s_nop 7\n\ts_nop 7" ::: "memory");

        if (kt0 == 2) {
            #pragma unroll
            for (int j = 0; j < 4; ++j)
                red[(wv & 3) * 256 + (4 * fg + j) * 16 + fc] = acc[j];
        }
        __syncthreads();
        if (kt0 == 0) {
            #pragma unroll
            for (int j = 0; j < 4; ++j) {
                float s = (acc[j] + red[(wv & 3) * 256 + (4 * fg + j) * 16 + fc]) * SCALE;
                aob[(size_t)(4 * fg + j) * SS + t * 64 + (wv & 3) * 16 + fc] = s;
            }
        }
        __syncthreads();  // red safe for next tile; k_s safe to restage
    }
    __syncthreads();  // all scores globally visible within block

    // ---- selection + softmax params (verified ballot bit-descent), 2 rows ----
    unsigned uv[2][16];
    #pragma unroll
    for (int rr = 0; rr < 2; ++rr) {
        const float* aor = aob + (size_t)(2 * wv + rr) * SS;
        #pragma unroll
        for (int t = 0; t < 16; ++t)
            uv[rr][t] = f2u_ord(aor[t * 64 + lane]);
    }
    unsigned pref[2]; int ecnt[2]; float mrow[2], invz[2], tvexp[2];
    #pragma unroll
    for (int rr = 0; rr < 2; ++rr) {
        unsigned p = 0;
        for (int bit = 31; bit >= 0; --bit) {
            unsigned cand = p | (1u << bit);
            int cnt = 0;
            #pragma unroll
            for (int t = 0; t < 16; ++t)
                cnt += __popcll(__ballot(uv[rr][t] >= cand));
            if (cnt >= KKTOP) p = cand;
        }
        pref[rr] = p;
        int g = 0;
        #pragma unroll
        for (int t = 0; t < 16; ++t)
            g += __popcll(__ballot(uv[rr][t] > p));
        ecnt[rr] = KKTOP - g;

        unsigned um = 0;
        #pragma unroll
        for (int t = 0; t < 16; ++t) um = um > uv[rr][t] ? um : uv[rr][t];
        #pragma unroll
        for (int o = 32; o > 0; o >>= 1) {
            unsigned tv2 = __shfl_down(um, o);
            um = um > tv2 ? um : tv2;
        }
        um = __shfl(um, 0);
        const float m = u2f_ord(um);

        float se = 0.f;
        #pragma unroll
        for (int t = 0; t < 16; ++t)
            if (uv[rr][t] > p) se += expf(u2f_ord(uv[rr][t]) - m);
        #pragma unroll
        for (int o = 32; o > 0; o >>= 1) se += __shfl_down(se, o);
        se = __shfl(se, 0);

        mrow[rr] = m;
        tvexp[rr] = expf(u2f_ord(p) - m);
        invz[rr] = 1.0f / (se + (float)ecnt[rr] * tvexp[rr]);
    }

    // ---- weights: attn_out final + wt bf16 (ties in (t,lane) index order) ----
    #pragma unroll
    for (int rr = 0; rr < 2; ++rr) {
        float* aor = aob + (size_t)(2 * wv + rr) * SS;
        unsigned short* wr = wt + (2 * wv + rr) * 1032;
        int tiesbefore = 0;
        #pragma unroll
        for (int t = 0; t < 16; ++t) {
            const unsigned u = uv[rr][t];
            const bool eq = (u == pref[rr]);
            unsigned long long mask = __ballot(eq);
            float w;
            if (u > pref[rr]) {
                w = expf(u2f_ord(u) - mrow[rr]) * invz[rr];
            } else if (eq) {
                int rank = tiesbefore + __popcll(mask & ((1ull << lane) - 1ull));
                w = (rank < ecnt[rr]) ? tvexp[rr] * invz[rr] : 0.f;
            } else {
                w = 0.f;
            }
            aor[t * 64 + lane] = w;
            wr[t * 64 + lane] = f2bf(w);
            tiesbefore += __popcll(mask);
        }
    }

    // ---- PV: ctx[16][128] = W[16][1024] @ V[1024][128] via bf16 MFMA ----
    f32x4 pacc = {0.f, 0.f, 0.f, 0.f};
    const int pvd = wv * 16 + fc;        // this lane's d column
    for (int t = 0; t < 16; ++t) {
        __syncthreads();   // wt complete (t=0) / prev vt reads done
        #pragma unroll
        for (int u = 0; u < 2; ++u) {
            int rem = tid + 512 * u;
            int d = rem >> 3, kc = rem & 7;
            su8 v = *(const su8*)(Vtg + (size_t)d * MROWS + t * 64 + kc * 8);
            *(su8*)&vt[d * 72 + ((kc ^ (d & 7)) * 8)] = v;
        }
        __syncthreads();
        #pragma unroll
        for (int kk = 0; kk < 2; ++kk) {
            su8 aw = *(const su8*)&wt[fc * 1032 + t * 64 + (kk * 4 + fg) * 8];
            su8 bv2 = *(const su8*)&vt[pvd * 72 + (((kk * 4 + fg) ^ (pvd & 7)) * 8)];
            asm volatile("v_mfma_f32_16x16x32_bf16 %0, %1, %2, %0"
                         : "+v"(pacc) : "v"(aw), "v"(bv2));
        }
    }
    asm volatile("s_nop 7\n\ts_nop 7" ::: "memory");

    #pragma unroll
    for (int j = 0; j < 4; ++j)
        CTX[(size_t)(b * SS + q0 + 4 * fg + j) * DD + h * DKK + pvd] = pacc[j];
}

// ---------------------------------------------------------------------------
extern "C" void kernel_launch(void* const* d_in, const int* in_sizes, int n_in,
                              void* d_out, int out_size, void* d_ws, size_t ws_size,
                              hipStream_t stream)
{
    const float* x  = (const float*)d_in[0];
    const float* Wq = (const float*)d_in[1];
    const float* bq = (const float*)d_in[2];
    const float* Wk = (const float*)d_in[3];
    const float* bk = (const float*)d_in[4];
    const float* Wv = (const float*)d_in[5];
    const float* bv = (const float*)d_in[6];
    const float* Wo = (const float*)d_in[7];
    const float* bo = (const float*)d_in[8];

    float* out      = (float*)d_out;                       // [4,1024,2048]
    float* attn_out = (float*)d_out + (size_t)MROWS * DD;  // [4,16,1024,1024]

    float* ws = (float*)d_ws;
    const size_t PLANE = (size_t)MROWS * DD;   // 8,388,608 floats
    float* Qb  = ws;                            // fp32
    float* Kb  = ws + PLANE;                    // fp32
    float* CTX = ws + 2 * PLANE;                // fp32
    unsigned short* Vtp = (unsigned short*)(ws + 3 * PLANE);  // bf16 [2048][4096]

    dim3 gb(MROWS / TM, DD / TN);   // (32,16)
    gemm_nt_f32<<<gb, 256, 0, stream>>>(x, Wq, bq, Qb, MROWS, DD, DD);
    gemm_nt_f32<<<gb, 256, 0, stream>>>(x, Wk, bk, Kb, MROWS, DD, DD);
    // transposed V-projection: Vt[vdim][token] = Wv @ x^T + bv (per-row bias)
    gemm_nt_bf16_tv<<<dim3(DD / TM, MROWS / TN), 256, 0, stream>>>(
        Wv, x, bv, Vtp, DD, MROWS, DD);

    // FIX (round 7 -> 8): grid must cover B*H*(S/16) = 4096 blocks.
    // Round-7 expression (MROWS/16*HH/16) evaluated to 256 -> 15/16 of the
    // output was never computed.
    attn_topk_fused<<<dim3(BB * HH * (SS / 16)), 512, 0, stream>>>(
        Qb, Kb, Vtp, attn_out, CTX);

    gemm_nt_bf16<<<gb, 256, 0, stream>>>(CTX, Wo, bo, out, MROWS, DD, DD);
}

// Round 9
// 1699.620 us; speedup vs baseline: 2.3518x; 1.0061x over previous
//
#include <hip/hip_runtime.h>
#include <math.h>

// Problem constants
#define BB 4
#define SS 1024
#define DD 2048
#define HH 16
#define DKK 128
#define KKTOP 307           // int(1024 * 0.3)
#define MROWS (BB * SS)     // 4096
#define KPLANE ((size_t)MROWS * DD)   // elements per K-split plane (8,388,608)
static __device__ __constant__ float SCALE = 0.08838834764831845f; // 1/sqrt(128)

typedef float f32x4 __attribute__((ext_vector_type(4)));
typedef unsigned short su4 __attribute__((ext_vector_type(4)));
typedef unsigned short su8 __attribute__((ext_vector_type(8)));

__device__ __forceinline__ unsigned short f2bf(float x) {   // RNE
    unsigned u = __float_as_uint(x);
    u += 0x7fffu + ((u >> 16) & 1u);
    return (unsigned short)(u >> 16);
}
__device__ __forceinline__ float bf2f(unsigned short b) {
    return __uint_as_float((unsigned)b << 16);
}
__device__ __forceinline__ unsigned f2u_ord(float f) {
    unsigned x = __float_as_uint(f);
    return (x & 0x80000000u) ? ~x : (x | 0x80000000u);
}
__device__ __forceinline__ float u2f_ord(unsigned u) {
    return __uint_as_float((u & 0x80000000u) ? (u & 0x7fffffffu) : ~u);
}
// 3-way bf16 split of fp32 (captures ~24 mantissa bits)
__device__ __forceinline__ void split4(float4 v, su4& a, su4& b, su4& c) {
    float x[4] = {v.x, v.y, v.z, v.w};
    #pragma unroll
    for (int i = 0; i < 4; ++i) {
        unsigned short b1 = f2bf(x[i]);
        float r = x[i] - bf2f(b1);
        unsigned short b2 = f2bf(r);
        float r2 = r - bf2f(b2);
        a[i] = b1; b[i] = b2; c[i] = f2bf(r2);
    }
}

// ---------------------------------------------------------------------------
// GEMM fp32 (round-1 verified, verbatim): Q projection.
// ---------------------------------------------------------------------------
#define TM 128
#define TN 128
#define TK 32
#define LDP (TM + 4)

__global__ __launch_bounds__(256) void gemm_nt_f32(
    const float* __restrict__ A, const float* __restrict__ W,
    const float* __restrict__ bias, float* __restrict__ C,
    int M, int N, int K)
{
    __shared__ float As[TK][LDP];
    __shared__ float Ws[TK][LDP];

    const int tid = threadIdx.x;
    const int bm = blockIdx.x * TM;
    const int bn = blockIdx.y * TN;
    const int tx = tid & 15;
    const int ty = tid >> 4;
    const int lr = tid >> 3;
    const int lk = (tid & 7) << 2;

    float acc[8][8];
    #pragma unroll
    for (int i = 0; i < 8; ++i)
        #pragma unroll
        for (int j = 0; j < 8; ++j) acc[i][j] = 0.f;

    for (int kt = 0; kt < K; kt += TK) {
        __syncthreads();
        const float* Ag = A + (size_t)(bm + lr) * K + kt + lk;
        const float* Wg = W + (size_t)(bn + lr) * K + kt + lk;
        #pragma unroll
        for (int m = 0; m < 4; ++m) {
            float4 av = *(const float4*)(Ag + (size_t)m * 32 * K);
            float4 wv = *(const float4*)(Wg + (size_t)m * 32 * K);
            int r = lr + m * 32;
            As[lk + 0][r] = av.x; As[lk + 1][r] = av.y;
            As[lk + 2][r] = av.z; As[lk + 3][r] = av.w;
            Ws[lk + 0][r] = wv.x; Ws[lk + 1][r] = wv.y;
            Ws[lk + 2][r] = wv.z; Ws[lk + 3][r] = wv.w;
        }
        __syncthreads();

        #pragma unroll
        for (int k = 0; k < TK; ++k) {
            float a[8], w[8];
            *(float4*)&a[0] = *(const float4*)&As[k][ty * 8];
            *(float4*)&a[4] = *(const float4*)&As[k][ty * 8 + 4];
            *(float4*)&w[0] = *(const float4*)&Ws[k][tx * 8];
            *(float4*)&w[4] = *(const float4*)&Ws[k][tx * 8 + 4];
            #pragma unroll
            for (int i = 0; i < 8; ++i)
                #pragma unroll
                for (int j = 0; j < 8; ++j)
                    acc[i][j] += a[i] * w[j];
        }
    }

    float bv[8];
    *(float4*)&bv[0] = *(const float4*)&bias[bn + tx * 8];
    *(float4*)&bv[4] = *(const float4*)&bias[bn + tx * 8 + 4];

    #pragma unroll
    for (int i = 0; i < 8; ++i) {
        float* cp = C + (size_t)(bm + ty * 8 + i) * N + bn + tx * 8;
        float4 o0 = make_float4(acc[i][0] + bv[0], acc[i][1] + bv[1],
                                acc[i][2] + bv[2], acc[i][3] + bv[3]);
        float4 o1 = make_float4(acc[i][4] + bv[4], acc[i][5] + bv[5],
                                acc[i][6] + bv[6], acc[i][7] + bv[7]);
        *(float4*)cp = o0;
        *(float4*)(cp + 4) = o1;
    }
}

// ---------------------------------------------------------------------------
// GEMM fp32 -> K-split epilogue: identical fp32 core; writes the 3 bf16
// split planes Ks[p][(b*HH+h)*SS + key][128] (head-aligned since TN=128).
// ---------------------------------------------------------------------------
__global__ __launch_bounds__(256) void gemm_nt_f32_ksplit(
    const float* __restrict__ A, const float* __restrict__ W,
    const float* __restrict__ bias, unsigned short* __restrict__ Ks,
    int M, int N, int K)
{
    __shared__ float As[TK][LDP];
    __shared__ float Ws[TK][LDP];

    const int tid = threadIdx.x;
    const int bm = blockIdx.x * TM;
    const int bn = blockIdx.y * TN;
    const int tx = tid & 15;
    const int ty = tid >> 4;
    const int lr = tid >> 3;
    const int lk = (tid & 7) << 2;

    float acc[8][8];
    #pragma unroll
    for (int i = 0; i < 8; ++i)
        #pragma unroll
        for (int j = 0; j < 8; ++j) acc[i][j] = 0.f;

    for (int kt = 0; kt < K; kt += TK) {
        __syncthreads();
        const float* Ag = A + (size_t)(bm + lr) * K + kt + lk;
        const float* Wg = W + (size_t)(bn + lr) * K + kt + lk;
        #pragma unroll
        for (int m = 0; m < 4; ++m) {
            float4 av = *(const float4*)(Ag + (size_t)m * 32 * K);
            float4 wv = *(const float4*)(Wg + (size_t)m * 32 * K);
            int r = lr + m * 32;
            As[lk + 0][r] = av.x; As[lk + 1][r] = av.y;
            As[lk + 2][r] = av.z; As[lk + 3][r] = av.w;
            Ws[lk + 0][r] = wv.x; Ws[lk + 1][r] = wv.y;
            Ws[lk + 2][r] = wv.z; Ws[lk + 3][r] = wv.w;
        }
        __syncthreads();

        #pragma unroll
        for (int k = 0; k < TK; ++k) {
            float a[8], w[8];
            *(float4*)&a[0] = *(const float4*)&As[k][ty * 8];
            *(float4*)&a[4] = *(const float4*)&As[k][ty * 8 + 4];
            *(float4*)&w[0] = *(const float4*)&Ws[k][tx * 8];
            *(float4*)&w[4] = *(const float4*)&Ws[k][tx * 8 + 4];
            #pragma unroll
            for (int i = 0; i < 8; ++i)
                #pragma unroll
                for (int j = 0; j < 8; ++j)
                    acc[i][j] += a[i] * w[j];
        }
    }

    float bv[8];
    *(float4*)&bv[0] = *(const float4*)&bias[bn + tx * 8];
    *(float4*)&bv[4] = *(const float4*)&bias[bn + tx * 8 + 4];

    const int hcol = bn >> 7;   // head index (TN == DKK == 128)
    #pragma unroll
    for (int i = 0; i < 8; ++i) {
        const int row = bm + ty * 8 + i;                 // token
        const size_t o = ((size_t)((row >> 10) * HH + hcol) * SS
                          + (row & (SS - 1))) * DKK + tx * 8;
        float4 lo = make_float4(acc[i][0] + bv[0], acc[i][1] + bv[1],
                                acc[i][2] + bv[2], acc[i][3] + bv[3]);
        float4 hi = make_float4(acc[i][4] + bv[4], acc[i][5] + bv[5],
                                acc[i][6] + bv[6], acc[i][7] + bv[7]);
        su4 a1, a2, a3, b1, b2, b3;
        split4(lo, a1, a2, a3);
        split4(hi, b1, b2, b3);
        *(su4*)&Ks[0 * KPLANE + o]     = a1;
        *(su4*)&Ks[0 * KPLANE + o + 4] = b1;
        *(su4*)&Ks[1 * KPLANE + o]     = a2;
        *(su4*)&Ks[1 * KPLANE + o + 4] = b2;
        *(su4*)&Ks[2 * KPLANE + o]     = a3;
        *(su4*)&Ks[2 * KPLANE + o + 4] = b3;
    }
}

// ---------------------------------------------------------------------------
// GEMM bf16-MFMA (round-6 verified, verbatim): fp32 in/out. Used for O-proj.
// ---------------------------------------------------------------------------
#define GLDA 40

__device__ __forceinline__ su8 pack8(float4 x, float4 y) {
    su8 r;
    r[0] = f2bf(x.x); r[1] = f2bf(x.y); r[2] = f2bf(x.z); r[3] = f2bf(x.w);
    r[4] = f2bf(y.x); r[5] = f2bf(y.y); r[6] = f2bf(y.z); r[7] = f2bf(y.w);
    return r;
}

__global__ __launch_bounds__(256) void gemm_nt_bf16(
    const float* __restrict__ A, const float* __restrict__ W,
    const float* __restrict__ bias, float* __restrict__ C,
    int M, int N, int K)
{
    __shared__ unsigned short Ab[128][GLDA];
    __shared__ unsigned short Bb[128][GLDA];

    const int tid = threadIdx.x;
    const int bm = blockIdx.x * 128;
    const int bn = blockIdx.y * 128;
    const int wm = (tid >> 6) & 1;
    const int wn = tid >> 7;
    const int lane = tid & 63;
    const int lrow = tid >> 1;
    const int lcol = (tid & 1) * 16;

    f32x4 acc[4][4];
    #pragma unroll
    for (int i = 0; i < 4; ++i)
        #pragma unroll
        for (int j = 0; j < 4; ++j)
            acc[i][j] = (f32x4){0.f, 0.f, 0.f, 0.f};

    for (int kt = 0; kt < K; kt += 32) {
        __syncthreads();
        {
            const float* Ag = A + (size_t)(bm + lrow) * K + kt + lcol;
            const float* Wg = W + (size_t)(bn + lrow) * K + kt + lcol;
            float4 a0 = *(const float4*)(Ag + 0);
            float4 a1 = *(const float4*)(Ag + 4);
            float4 a2 = *(const float4*)(Ag + 8);
            float4 a3 = *(const float4*)(Ag + 12);
            *(su8*)&Ab[lrow][lcol + 0] = pack8(a0, a1);
            *(su8*)&Ab[lrow][lcol + 8] = pack8(a2, a3);
            float4 b0 = *(const float4*)(Wg + 0);
            float4 b1 = *(const float4*)(Wg + 4);
            float4 b2 = *(const float4*)(Wg + 8);
            float4 b3 = *(const float4*)(Wg + 12);
            *(su8*)&Bb[lrow][lcol + 0] = pack8(b0, b1);
            *(su8*)&Bb[lrow][lcol + 8] = pack8(b2, b3);
        }
        __syncthreads();

        su8 af[4], bf[4];
        #pragma unroll
        for (int f = 0; f < 4; ++f) {
            af[f] = *(const su8*)&Ab[wm * 64 + f * 16 + (lane & 15)][(lane >> 4) * 8];
            bf[f] = *(const su8*)&Bb[wn * 64 + f * 16 + (lane & 15)][(lane >> 4) * 8];
        }
        #pragma unroll
        for (int fi = 0; fi < 4; ++fi)
            #pragma unroll
            for (int fj = 0; fj < 4; ++fj)
                asm volatile("v_mfma_f32_16x16x32_bf16 %0, %1, %2, %0"
                             : "+v"(acc[fi][fj])
                             : "v"(af[fi]), "v"(bf[fj]));
    }

    asm volatile("s_nop 7\n\ts_nop 7" ::: "memory");

    #pragma unroll
    for (int fj = 0; fj < 4; ++fj) {
        const int col = bn + wn * 64 + fj * 16 + (lane & 15);
        const float bv = bias[col];
        #pragma unroll
        for (int fi = 0; fi < 4; ++fi) {
            const int r0 = bm + wm * 64 + fi * 16 + (lane >> 4) * 4;
            #pragma unroll
            for (int j = 0; j < 4; ++j)
                C[(size_t)(r0 + j) * N + col] = acc[fi][fj][j] + bv;
        }
    }
}

// ---------------------------------------------------------------------------
// GEMM bf16-MFMA, transposed-V variant (round-8 verified, verbatim).
// ---------------------------------------------------------------------------
__global__ __launch_bounds__(256) void gemm_nt_bf16_tv(
    const float* __restrict__ A, const float* __restrict__ W,
    const float* __restrict__ bias, unsigned short* __restrict__ Cb,
    int M, int N, int K)
{
    __shared__ unsigned short Ab[128][GLDA];
    __shared__ unsigned short Bb[128][GLDA];

    const int tid = threadIdx.x;
    const int bm = blockIdx.x * 128;
    const int bn = blockIdx.y * 128;
    const int wm = (tid >> 6) & 1;
    const int wn = tid >> 7;
    const int lane = tid & 63;
    const int lrow = tid >> 1;
    const int lcol = (tid & 1) * 16;

    f32x4 acc[4][4];
    #pragma unroll
    for (int i = 0; i < 4; ++i)
        #pragma unroll
        for (int j = 0; j < 4; ++j)
            acc[i][j] = (f32x4){0.f, 0.f, 0.f, 0.f};

    for (int kt = 0; kt < K; kt += 32) {
        __syncthreads();
        {
            const float* Ag = A + (size_t)(bm + lrow) * K + kt + lcol;
            const float* Wg = W + (size_t)(bn + lrow) * K + kt + lcol;
            float4 a0 = *(const float4*)(Ag + 0);
            float4 a1 = *(const float4*)(Ag + 4);
            float4 a2 = *(const float4*)(Ag + 8);
            float4 a3 = *(const float4*)(Ag + 12);
            *(su8*)&Ab[lrow][lcol + 0] = pack8(a0, a1);
            *(su8*)&Ab[lrow][lcol + 8] = pack8(a2, a3);
            float4 b0 = *(const float4*)(Wg + 0);
            float4 b1 = *(const float4*)(Wg + 4);
            float4 b2 = *(const float4*)(Wg + 8);
            float4 b3 = *(const float4*)(Wg + 12);
            *(su8*)&Bb[lrow][lcol + 0] = pack8(b0, b1);
            *(su8*)&Bb[lrow][lcol + 8] = pack8(b2, b3);
        }
        __syncthreads();

        su8 af[4], bf[4];
        #pragma unroll
        for (int f = 0; f < 4; ++f) {
            af[f] = *(const su8*)&Ab[wm * 64 + f * 16 + (lane & 15)][(lane >> 4) * 8];
            bf[f] = *(const su8*)&Bb[wn * 64 + f * 16 + (lane & 15)][(lane >> 4) * 8];
        }
        #pragma unroll
        for (int fi = 0; fi < 4; ++fi)
            #pragma unroll
            for (int fj = 0; fj < 4; ++fj)
                asm volatile("v_mfma_f32_16x16x32_bf16 %0, %1, %2, %0"
                             : "+v"(acc[fi][fj])
                             : "v"(af[fi]), "v"(bf[fj]));
    }

    asm volatile("s_nop 7\n\ts_nop 7" ::: "memory");

    #pragma unroll
    for (int fj = 0; fj < 4; ++fj) {
        const int col = bn + wn * 64 + fj * 16 + (lane & 15);
        #pragma unroll
        for (int fi = 0; fi < 4; ++fi) {
            const int r0 = bm + wm * 64 + fi * 16 + (lane >> 4) * 4;
            #pragma unroll
            for (int j = 0; j < 4; ++j) {
                float v = acc[fi][fj][j] + bias[r0 + j];
                Cb[(size_t)(r0 + j) * N + col] = f2bf(v);
            }
        }
    }
}

// ---------------------------------------------------------------------------
// Fused attn (round-8 verified structure). Change: K splits are PRE-COMPUTED
// (by gemm_nt_f32_ksplit) -> staging is pure su8 copies, no split4 VALU.
// ---------------------------------------------------------------------------
#define ATT_LDS 65280

__global__ __launch_bounds__(512) void attn_topk_fused(
    const float* __restrict__ Qb, const unsigned short* __restrict__ Ks,
    const unsigned short* __restrict__ Vt, float* __restrict__ attn_out,
    float* __restrict__ CTX)
{
    __shared__ __align__(16) char smem[ATT_LDS];
    unsigned short* q_s = (unsigned short*)smem;                   // [3][16][136]
    unsigned short* k_s = (unsigned short*)(smem + 13056);         // [3][64][136]
    float*          red = (float*)smem;                            // [4][16][16]
    unsigned short* wt  = (unsigned short*)(smem + 13056);         // [16][1032]
    unsigned short* vt  = (unsigned short*)(smem + 13056 + 33024); // [128][72]

    const int tid = threadIdx.x;
    const int wv = tid >> 6, lane = tid & 63;
    const int fg = lane >> 4, fc = lane & 15;

    // XCD-chunked bijective remap: 4096 = 8 XCDs x 512
    const int gg = (blockIdx.x & 7) * 512 + ((int)blockIdx.x >> 3);
    const int bh = gg >> 6, qb = gg & 63;
    const int b = bh >> 4, h = bh & 15;
    const int q0 = qb * 16;

    const float* Qg = Qb + (size_t)(b * SS + q0) * DD + h * DKK;
    const unsigned short* Ksg = Ks + (size_t)bh * SS * DKK;
    const unsigned short* Vtg = Vt + (size_t)(h * DKK) * MROWS + b * SS;
    float* aob = attn_out + (size_t)(bh * SS + q0) * SS;

    // ---- stage Q splits (once): 512 units = 16 rows x 32 c4 ----
    {
        int row = tid >> 5, c4 = tid & 31;
        float4 v = *(const float4*)(Qg + (size_t)row * DD + c4 * 4);
        int off = row * 136 + (((c4 >> 1) ^ (row & 7)) * 8) + (c4 & 1) * 4;
        su4 p1, p2, p3; split4(v, p1, p2, p3);
        *(su4*)&q_s[off] = p1;
        *(su4*)&q_s[2176 + off] = p2;
        *(su4*)&q_s[4352 + off] = p3;
    }
    __syncthreads();

    // ---- persistent A-frags: af[split][ktile-of-my-dhalf] ----
    const int kt0 = (wv >> 2) * 2;   // ktile base: 0 (d 0..63) or 2 (d 64..127)
    su8 af[3][2];
    #pragma unroll
    for (int p = 0; p < 3; ++p)
        #pragma unroll
        for (int kk = 0; kk < 2; ++kk)
            af[p][kk] = *(const su8*)&q_s[p * 2176 + fc * 136 +
                            ((((kt0 + kk) * 4 + fg) ^ (fc & 7)) * 8)];

    // ---- scores over 16 key-tiles of 64 ----
    for (int t = 0; t < 16; ++t) {
        // stage pre-split K tile: pure copies (p = pu>>1, u = pu&1)
        #pragma unroll
        for (int pu = 0; pu < 6; ++pu) {
            const int p = pu >> 1;
            const int rem = tid + 512 * (pu & 1);
            const int row = rem >> 4, c8 = rem & 15;
            su8 v = *(const su8*)(Ksg + p * KPLANE +
                                  (size_t)(t * 64 + row) * DKK + c8 * 8);
            *(su8*)&k_s[p * 8704 + row * 136 + ((c8 ^ (row & 7)) * 8)] = v;
        }
        __syncthreads();

        const int krow = (wv & 3) * 16 + fc;
        su8 bf[3][2];
        #pragma unroll
        for (int p = 0; p < 3; ++p)
            #pragma unroll
            for (int kk = 0; kk < 2; ++kk)
                bf[p][kk] = *(const su8*)&k_s[p * 8704 + krow * 136 +
                                ((((kt0 + kk) * 4 + fg) ^ (krow & 7)) * 8)];

        f32x4 acc = {0.f, 0.f, 0.f, 0.f};
        // passes small->large: (q3,k1),(q1,k3),(q2,k2),(q2,k1),(q1,k2),(q1,k1)
        constexpr int PI[6] = {2, 0, 1, 1, 0, 0};
        constexpr int PJ[6] = {0, 2, 1, 0, 1, 0};
        #pragma unroll
        for (int p = 0; p < 6; ++p)
            #pragma unroll
            for (int kk = 0; kk < 2; ++kk)
                asm volatile("v_mfma_f32_16x16x32_bf16 %0, %1, %2, %0"
                             : "+v"(acc) : "v"(af[PI[p]][kk]), "v"(bf[PJ[p]][kk]));
        asm volatile("s_nop 7\n\ts_nop 7" ::: "memory");

        if (kt0 == 2) {
            #pragma unroll
            for (int j = 0; j < 4; ++j)
                red[(wv & 3) * 256 + (4 * fg + j) * 16 + fc] = acc[j];
        }
        __syncthreads();
        if (kt0 == 0) {
            #pragma unroll
            for (int j = 0; j < 4; ++j) {
                float s = (acc[j] + red[(wv & 3) * 256 + (4 * fg + j) * 16 + fc]) * SCALE;
                aob[(size_t)(4 * fg + j) * SS + t * 64 + (wv & 3) * 16 + fc] = s;
            }
        }
        __syncthreads();  // red safe for next tile; k_s safe to restage
    }
    __syncthreads();  // all scores visible within block

    // ---- selection + softmax params (verified ballot bit-descent), 2 rows ----
    unsigned uv[2][16];
    #pragma unroll
    for (int rr = 0; rr < 2; ++rr) {
        const float* aor = aob + (size_t)(2 * wv + rr) * SS;
        #pragma unroll
        for (int t = 0; t < 16; ++t)
            uv[rr][t] = f2u_ord(aor[t * 64 + lane]);
    }
    unsigned pref[2]; int ecnt[2]; float mrow[2], invz[2], tvexp[2];
    #pragma unroll
    for (int rr = 0; rr < 2; ++rr) {
        unsigned p = 0;
        for (int bit = 31; bit >= 0; --bit) {
            unsigned cand = p | (1u << bit);
            int cnt = 0;
            #pragma unroll
            for (int t = 0; t < 16; ++t)
                cnt += __popcll(__ballot(uv[rr][t] >= cand));
            if (cnt >= KKTOP) p = cand;
        }
        pref[rr] = p;
        int g = 0;
        #pragma unroll
        for (int t = 0; t < 16; ++t)
            g += __popcll(__ballot(uv[rr][t] > p));
        ecnt[rr] = KKTOP - g;

        unsigned um = 0;
        #pragma unroll
        for (int t = 0; t < 16; ++t) um = um > uv[rr][t] ? um : uv[rr][t];
        #pragma unroll
        for (int o = 32; o > 0; o >>= 1) {
            unsigned tv2 = __shfl_down(um, o);
            um = um > tv2 ? um : tv2;
        }
        um = __shfl(um, 0);
        const float m = u2f_ord(um);

        float se = 0.f;
        #pragma unroll
        for (int t = 0; t < 16; ++t)
            if (uv[rr][t] > p) se += expf(u2f_ord(uv[rr][t]) - m);
        #pragma unroll
        for (int o = 32; o > 0; o >>= 1) se += __shfl_down(se, o);
        se = __shfl(se, 0);

        mrow[rr] = m;
        tvexp[rr] = expf(u2f_ord(p) - m);
        invz[rr] = 1.0f / (se + (float)ecnt[rr] * tvexp[rr]);
    }

    // ---- weights: attn_out final + wt bf16 (ties in (t,lane) index order) ----
    #pragma unroll
    for (int rr = 0; rr < 2; ++rr) {
        float* aor = aob + (size_t)(2 * wv + rr) * SS;
        unsigned short* wr = wt + (2 * wv + rr) * 1032;
        int tiesbefore = 0;
        #pragma unroll
        for (int t = 0; t < 16; ++t) {
            const unsigned u = uv[rr][t];
            const bool eq = (u == pref[rr]);
            unsigned long long mask = __ballot(eq);
            float w;
            if (u > pref[rr]) {
                w = expf(u2f_ord(u) - mrow[rr]) * invz[rr];
            } else if (eq) {
                int rank = tiesbefore + __popcll(mask & ((1ull << lane) - 1ull));
                w = (rank < ecnt[rr]) ? tvexp[rr] * invz[rr] : 0.f;
            } else {
                w = 0.f;
            }
            aor[t * 64 + lane] = w;
            wr[t * 64 + lane] = f2bf(w);
            tiesbefore += __popcll(mask);
        }
    }

    // ---- PV: ctx[16][128] = W[16][1024] @ V[1024][128] via bf16 MFMA ----
    f32x4 pacc = {0.f, 0.f, 0.f, 0.f};
    const int pvd = wv * 16 + fc;        // this lane's d column
    for (int t = 0; t < 16; ++t) {
        __syncthreads();   // wt complete (t=0) / prev vt reads done
        #pragma unroll
        for (int u = 0; u < 2; ++u) {
            int rem = tid + 512 * u;
            int d = rem >> 3, kc = rem & 7;
            su8 v = *(const su8*)(Vtg + (size_t)d * MROWS + t * 64 + kc * 8);
            *(su8*)&vt[d * 72 + ((kc ^ (d & 7)) * 8)] = v;
        }
        __syncthreads();
        #pragma unroll
        for (int kk = 0; kk < 2; ++kk) {
            su8 aw = *(const su8*)&wt[fc * 1032 + t * 64 + (kk * 4 + fg) * 8];
            su8 bv2 = *(const su8*)&vt[pvd * 72 + (((kk * 4 + fg) ^ (pvd & 7)) * 8)];
            asm volatile("v_mfma_f32_16x16x32_bf16 %0, %1, %2, %0"
                         : "+v"(pacc) : "v"(aw), "v"(bv2));
        }
    }
    asm volatile("s_nop 7\n\ts_nop 7" ::: "memory");

    #pragma unroll
    for (int j = 0; j < 4; ++j)
        CTX[(size_t)(b * SS + q0 + 4 * fg + j) * DD + h * DKK + pvd] = pacc[j];
}

// ---------------------------------------------------------------------------
extern "C" void kernel_launch(void* const* d_in, const int* in_sizes, int n_in,
                              void* d_out, int out_size, void* d_ws, size_t ws_size,
                              hipStream_t stream)
{
    const float* x  = (const float*)d_in[0];
    const float* Wq = (const float*)d_in[1];
    const float* bq = (const float*)d_in[2];
    const float* Wk = (const float*)d_in[3];
    const float* bk = (const float*)d_in[4];
    const float* Wv = (const float*)d_in[5];
    const float* bv = (const float*)d_in[6];
    const float* Wo = (const float*)d_in[7];
    const float* bo = (const float*)d_in[8];

    float* out      = (float*)d_out;                       // [4,1024,2048]
    float* attn_out = (float*)d_out + (size_t)MROWS * DD;  // [4,16,1024,1024]

    float* ws = (float*)d_ws;
    const size_t PLANE = (size_t)MROWS * DD;   // 8,388,608
    // ws carve (134.2 MB total == round-1's proven footprint):
    //   [Qb fp32: PLANE][Ks bf16: 3*PLANE (=1.5 PLANE floats)][CTX fp32: PLANE]
    //   [Vt bf16: PLANE (=0.5 PLANE floats)]
    float* Qb = ws;
    unsigned short* Ksp = (unsigned short*)(ws + PLANE);
    float* CTX = ws + PLANE + PLANE * 3 / 2;
    unsigned short* Vtp = (unsigned short*)(ws + PLANE + PLANE * 3 / 2 + PLANE);

    dim3 gb(MROWS / TM, DD / TN);   // (32,16)
    gemm_nt_f32<<<gb, 256, 0, stream>>>(x, Wq, bq, Qb, MROWS, DD, DD);
    gemm_nt_f32_ksplit<<<gb, 256, 0, stream>>>(x, Wk, bk, Ksp, MROWS, DD, DD);
    // transposed V-projection: Vt[vdim][token] = Wv @ x^T + bv (per-row bias)
    gemm_nt_bf16_tv<<<dim3(DD / TM, MROWS / TN), 256, 0, stream>>>(
        Wv, x, bv, Vtp, DD, MROWS, DD);

    attn_topk_fused<<<dim3(BB * HH * (SS / 16)), 512, 0, stream>>>(
        Qb, Ksp, Vtp, attn_out, CTX);

    gemm_nt_bf16<<<gb, 256, 0, stream>>>(CTX, Wo, bo, out, MROWS, DD, DD);
}

// Round 11
// 1665.968 us; speedup vs baseline: 2.3993x; 1.0202x over previous
//
#include <hip/hip_runtime.h>
#include <math.h>

// Problem constants
#define BB 4
#define SS 1024
#define DD 2048
#define HH 16
#define DKK 128
#define KKTOP 307           // int(1024 * 0.3)
#define MROWS (BB * SS)     // 4096
#define KPLANE ((size_t)MROWS * DD)   // elements per K-split plane (8,388,608)
static __device__ __constant__ float SCALE = 0.08838834764831845f; // 1/sqrt(128)

typedef float f32x4 __attribute__((ext_vector_type(4)));
typedef unsigned short su4 __attribute__((ext_vector_type(4)));
typedef unsigned short su8 __attribute__((ext_vector_type(8)));

__device__ __forceinline__ unsigned short f2bf(float x) {   // RNE
    unsigned u = __float_as_uint(x);
    u += 0x7fffu + ((u >> 16) & 1u);
    return (unsigned short)(u >> 16);
}
__device__ __forceinline__ float bf2f(unsigned short b) {
    return __uint_as_float((unsigned)b << 16);
}
__device__ __forceinline__ unsigned f2u_ord(float f) {
    unsigned x = __float_as_uint(f);
    return (x & 0x80000000u) ? ~x : (x | 0x80000000u);
}
__device__ __forceinline__ float u2f_ord(unsigned u) {
    return __uint_as_float((u & 0x80000000u) ? (u & 0x7fffffffu) : ~u);
}
// 3-way bf16 split of fp32 (captures ~24 mantissa bits)
__device__ __forceinline__ void split4(float4 v, su4& a, su4& b, su4& c) {
    float x[4] = {v.x, v.y, v.z, v.w};
    #pragma unroll
    for (int i = 0; i < 4; ++i) {
        unsigned short b1 = f2bf(x[i]);
        float r = x[i] - bf2f(b1);
        unsigned short b2 = f2bf(r);
        float r2 = r - bf2f(b2);
        a[i] = b1; b[i] = b2; c[i] = f2bf(r2);
    }
}

// ---------------------------------------------------------------------------
// GEMM fp32 (round-1 verified, verbatim): Q projection.
// ---------------------------------------------------------------------------
#define TM 128
#define TN 128
#define TK 32
#define LDP (TM + 4)

__global__ __launch_bounds__(256) void gemm_nt_f32(
    const float* __restrict__ A, const float* __restrict__ W,
    const float* __restrict__ bias, float* __restrict__ C,
    int M, int N, int K)
{
    __shared__ float As[TK][LDP];
    __shared__ float Ws[TK][LDP];

    const int tid = threadIdx.x;
    const int bm = blockIdx.x * TM;
    const int bn = blockIdx.y * TN;
    const int tx = tid & 15;
    const int ty = tid >> 4;
    const int lr = tid >> 3;
    const int lk = (tid & 7) << 2;

    float acc[8][8];
    #pragma unroll
    for (int i = 0; i < 8; ++i)
        #pragma unroll
        for (int j = 0; j < 8; ++j) acc[i][j] = 0.f;

    for (int kt = 0; kt < K; kt += TK) {
        __syncthreads();
        const float* Ag = A + (size_t)(bm + lr) * K + kt + lk;
        const float* Wg = W + (size_t)(bn + lr) * K + kt + lk;
        #pragma unroll
        for (int m = 0; m < 4; ++m) {
            float4 av = *(const float4*)(Ag + (size_t)m * 32 * K);
            float4 wv = *(const float4*)(Wg + (size_t)m * 32 * K);
            int r = lr + m * 32;
            As[lk + 0][r] = av.x; As[lk + 1][r] = av.y;
            As[lk + 2][r] = av.z; As[lk + 3][r] = av.w;
            Ws[lk + 0][r] = wv.x; Ws[lk + 1][r] = wv.y;
            Ws[lk + 2][r] = wv.z; Ws[lk + 3][r] = wv.w;
        }
        __syncthreads();

        #pragma unroll
        for (int k = 0; k < TK; ++k) {
            float a[8], w[8];
            *(float4*)&a[0] = *(const float4*)&As[k][ty * 8];
            *(float4*)&a[4] = *(const float4*)&As[k][ty * 8 + 4];
            *(float4*)&w[0] = *(const float4*)&Ws[k][tx * 8];
            *(float4*)&w[4] = *(const float4*)&Ws[k][tx * 8 + 4];
            #pragma unroll
            for (int i = 0; i < 8; ++i)
                #pragma unroll
                for (int j = 0; j < 8; ++j)
                    acc[i][j] += a[i] * w[j];
        }
    }

    float bv[8];
    *(float4*)&bv[0] = *(const float4*)&bias[bn + tx * 8];
    *(float4*)&bv[4] = *(const float4*)&bias[bn + tx * 8 + 4];

    #pragma unroll
    for (int i = 0; i < 8; ++i) {
        float* cp = C + (size_t)(bm + ty * 8 + i) * N + bn + tx * 8;
        float4 o0 = make_float4(acc[i][0] + bv[0], acc[i][1] + bv[1],
                                acc[i][2] + bv[2], acc[i][3] + bv[3]);
        float4 o1 = make_float4(acc[i][4] + bv[4], acc[i][5] + bv[5],
                                acc[i][6] + bv[6], acc[i][7] + bv[7]);
        *(float4*)cp = o0;
        *(float4*)(cp + 4) = o1;
    }
}

// ---------------------------------------------------------------------------
// GEMM fp32 -> K-split epilogue (round-9 verified, verbatim).
// ---------------------------------------------------------------------------
__global__ __launch_bounds__(256) void gemm_nt_f32_ksplit(
    const float* __restrict__ A, const float* __restrict__ W,
    const float* __restrict__ bias, unsigned short* __restrict__ Ks,
    int M, int N, int K)
{
    __shared__ float As[TK][LDP];
    __shared__ float Ws[TK][LDP];

    const int tid = threadIdx.x;
    const int bm = blockIdx.x * TM;
    const int bn = blockIdx.y * TN;
    const int tx = tid & 15;
    const int ty = tid >> 4;
    const int lr = tid >> 3;
    const int lk = (tid & 7) << 2;

    float acc[8][8];
    #pragma unroll
    for (int i = 0; i < 8; ++i)
        #pragma unroll
        for (int j = 0; j < 8; ++j) acc[i][j] = 0.f;

    for (int kt = 0; kt < K; kt += TK) {
        __syncthreads();
        const float* Ag = A + (size_t)(bm + lr) * K + kt + lk;
        const float* Wg = W + (size_t)(bn + lr) * K + kt + lk;
        #pragma unroll
        for (int m = 0; m < 4; ++m) {
            float4 av = *(const float4*)(Ag + (size_t)m * 32 * K);
            float4 wv = *(const float4*)(Wg + (size_t)m * 32 * K);
            int r = lr + m * 32;
            As[lk + 0][r] = av.x; As[lk + 1][r] = av.y;
            As[lk + 2][r] = av.z; As[lk + 3][r] = av.w;
            Ws[lk + 0][r] = wv.x; Ws[lk + 1][r] = wv.y;
            Ws[lk + 2][r] = wv.z; Ws[lk + 3][r] = wv.w;
        }
        __syncthreads();

        #pragma unroll
        for (int k = 0; k < TK; ++k) {
            float a[8], w[8];
            *(float4*)&a[0] = *(const float4*)&As[k][ty * 8];
            *(float4*)&a[4] = *(const float4*)&As[k][ty * 8 + 4];
            *(float4*)&w[0] = *(const float4*)&Ws[k][tx * 8];
            *(float4*)&w[4] = *(const float4*)&Ws[k][tx * 8 + 4];
            #pragma unroll
            for (int i = 0; i < 8; ++i)
                #pragma unroll
                for (int j = 0; j < 8; ++j)
                    acc[i][j] += a[i] * w[j];
        }
    }

    float bv[8];
    *(float4*)&bv[0] = *(const float4*)&bias[bn + tx * 8];
    *(float4*)&bv[4] = *(const float4*)&bias[bn + tx * 8 + 4];

    const int hcol = bn >> 7;   // head index (TN == DKK == 128)
    #pragma unroll
    for (int i = 0; i < 8; ++i) {
        const int row = bm + ty * 8 + i;                 // token
        const size_t o = ((size_t)((row >> 10) * HH + hcol) * SS
                          + (row & (SS - 1))) * DKK + tx * 8;
        float4 lo = make_float4(acc[i][0] + bv[0], acc[i][1] + bv[1],
                                acc[i][2] + bv[2], acc[i][3] + bv[3]);
        float4 hi = make_float4(acc[i][4] + bv[4], acc[i][5] + bv[5],
                                acc[i][6] + bv[6], acc[i][7] + bv[7]);
        su4 a1, a2, a3, b1, b2, b3;
        split4(lo, a1, a2, a3);
        split4(hi, b1, b2, b3);
        *(su4*)&Ks[0 * KPLANE + o]     = a1;
        *(su4*)&Ks[0 * KPLANE + o + 4] = b1;
        *(su4*)&Ks[1 * KPLANE + o]     = a2;
        *(su4*)&Ks[1 * KPLANE + o + 4] = b2;
        *(su4*)&Ks[2 * KPLANE + o]     = a3;
        *(su4*)&Ks[2 * KPLANE + o + 4] = b3;
    }
}

// ---------------------------------------------------------------------------
// GEMM bf16-MFMA (round-6 verified, verbatim): fp32 in/out. Used for O-proj.
// ---------------------------------------------------------------------------
#define GLDA 40

__device__ __forceinline__ su8 pack8(float4 x, float4 y) {
    su8 r;
    r[0] = f2bf(x.x); r[1] = f2bf(x.y); r[2] = f2bf(x.z); r[3] = f2bf(x.w);
    r[4] = f2bf(y.x); r[5] = f2bf(y.y); r[6] = f2bf(y.z); r[7] = f2bf(y.w);
    return r;
}

__global__ __launch_bounds__(256) void gemm_nt_bf16(
    const float* __restrict__ A, const float* __restrict__ W,
    const float* __restrict__ bias, float* __restrict__ C,
    int M, int N, int K)
{
    __shared__ unsigned short Ab[128][GLDA];
    __shared__ unsigned short Bb[128][GLDA];

    const int tid = threadIdx.x;
    const int bm = blockIdx.x * 128;
    const int bn = blockIdx.y * 128;
    const int wm = (tid >> 6) & 1;
    const int wn = tid >> 7;
    const int lane = tid & 63;
    const int lrow = tid >> 1;
    const int lcol = (tid & 1) * 16;

    f32x4 acc[4][4];
    #pragma unroll
    for (int i = 0; i < 4; ++i)
        #pragma unroll
        for (int j = 0; j < 4; ++j)
            acc[i][j] = (f32x4){0.f, 0.f, 0.f, 0.f};

    for (int kt = 0; kt < K; kt += 32) {
        __syncthreads();
        {
            const float* Ag = A + (size_t)(bm + lrow) * K + kt + lcol;
            const float* Wg = W + (size_t)(bn + lrow) * K + kt + lcol;
            float4 a0 = *(const float4*)(Ag + 0);
            float4 a1 = *(const float4*)(Ag + 4);
            float4 a2 = *(const float4*)(Ag + 8);
            float4 a3 = *(const float4*)(Ag + 12);
            *(su8*)&Ab[lrow][lcol + 0] = pack8(a0, a1);
            *(su8*)&Ab[lrow][lcol + 8] = pack8(a2, a3);
            float4 b0 = *(const float4*)(Wg + 0);
            float4 b1 = *(const float4*)(Wg + 4);
            float4 b2 = *(const float4*)(Wg + 8);
            float4 b3 = *(const float4*)(Wg + 12);
            *(su8*)&Bb[lrow][lcol + 0] = pack8(b0, b1);
            *(su8*)&Bb[lrow][lcol + 8] = pack8(b2, b3);
        }
        __syncthreads();

        su8 af[4], bf[4];
        #pragma unroll
        for (int f = 0; f < 4; ++f) {
            af[f] = *(const su8*)&Ab[wm * 64 + f * 16 + (lane & 15)][(lane >> 4) * 8];
            bf[f] = *(const su8*)&Bb[wn * 64 + f * 16 + (lane & 15)][(lane >> 4) * 8];
        }
        #pragma unroll
        for (int fi = 0; fi < 4; ++fi)
            #pragma unroll
            for (int fj = 0; fj < 4; ++fj)
                asm volatile("v_mfma_f32_16x16x32_bf16 %0, %1, %2, %0"
                             : "+v"(acc[fi][fj])
                             : "v"(af[fi]), "v"(bf[fj]));
    }

    asm volatile("s_nop 7\n\ts_nop 7" ::: "memory");

    #pragma unroll
    for (int fj = 0; fj < 4; ++fj) {
        const int col = bn + wn * 64 + fj * 16 + (lane & 15);
        const float bv = bias[col];
        #pragma unroll
        for (int fi = 0; fi < 4; ++fi) {
            const int r0 = bm + wm * 64 + fi * 16 + (lane >> 4) * 4;
            #pragma unroll
            for (int j = 0; j < 4; ++j)
                C[(size_t)(r0 + j) * N + col] = acc[fi][fj][j] + bv;
        }
    }
}

// ---------------------------------------------------------------------------
// GEMM bf16-MFMA, transposed-V variant (round-8 verified, verbatim).
// ---------------------------------------------------------------------------
__global__ __launch_bounds__(256) void gemm_nt_bf16_tv(
    const float* __restrict__ A, const float* __restrict__ W,
    const float* __restrict__ bias, unsigned short* __restrict__ Cb,
    int M, int N, int K)
{
    __shared__ unsigned short Ab[128][GLDA];
    __shared__ unsigned short Bb[128][GLDA];

    const int tid = threadIdx.x;
    const int bm = blockIdx.x * 128;
    const int bn = blockIdx.y * 128;
    const int wm = (tid >> 6) & 1;
    const int wn = tid >> 7;
    const int lane = tid & 63;
    const int lrow = tid >> 1;
    const int lcol = (tid & 1) * 16;

    f32x4 acc[4][4];
    #pragma unroll
    for (int i = 0; i < 4; ++i)
        #pragma unroll
        for (int j = 0; j < 4; ++j)
            acc[i][j] = (f32x4){0.f, 0.f, 0.f, 0.f};

    for (int kt = 0; kt < K; kt += 32) {
        __syncthreads();
        {
            const float* Ag = A + (size_t)(bm + lrow) * K + kt + lcol;
            const float* Wg = W + (size_t)(bn + lrow) * K + kt + lcol;
            float4 a0 = *(const float4*)(Ag + 0);
            float4 a1 = *(const float4*)(Ag + 4);
            float4 a2 = *(const float4*)(Ag + 8);
            float4 a3 = *(const float4*)(Ag + 12);
            *(su8*)&Ab[lrow][lcol + 0] = pack8(a0, a1);
            *(su8*)&Ab[lrow][lcol + 8] = pack8(a2, a3);
            float4 b0 = *(const float4*)(Wg + 0);
            float4 b1 = *(const float4*)(Wg + 4);
            float4 b2 = *(const float4*)(Wg + 8);
            float4 b3 = *(const float4*)(Wg + 12);
            *(su8*)&Bb[lrow][lcol + 0] = pack8(b0, b1);
            *(su8*)&Bb[lrow][lcol + 8] = pack8(b2, b3);
        }
        __syncthreads();

        su8 af[4], bf[4];
        #pragma unroll
        for (int f = 0; f < 4; ++f) {
            af[f] = *(const su8*)&Ab[wm * 64 + f * 16 + (lane & 15)][(lane >> 4) * 8];
            bf[f] = *(const su8*)&Bb[wn * 64 + f * 16 + (lane & 15)][(lane >> 4) * 8];
        }
        #pragma unroll
        for (int fi = 0; fi < 4; ++fi)
            #pragma unroll
            for (int fj = 0; fj < 4; ++fj)
                asm volatile("v_mfma_f32_16x16x32_bf16 %0, %1, %2, %0"
                             : "+v"(acc[fi][fj])
                             : "v"(af[fi]), "v"(bf[fj]));
    }

    asm volatile("s_nop 7\n\ts_nop 7" ::: "memory");

    #pragma unroll
    for (int fj = 0; fj < 4; ++fj) {
        const int col = bn + wn * 64 + fj * 16 + (lane & 15);
        #pragma unroll
        for (int fi = 0; fi < 4; ++fi) {
            const int r0 = bm + wm * 64 + fi * 16 + (lane >> 4) * 4;
            #pragma unroll
            for (int j = 0; j < 4; ++j) {
                float v = acc[fi][fj][j] + bias[r0 + j];
                Cb[(size_t)(r0 + j) * N + col] = f2bf(v);
            }
        }
    }
}

// ---------------------------------------------------------------------------
// Fused attn — round-9 verified kernel, ONLY change: XOR removed from all
// LDS addressing (stride-136/72 row rotation alone gives free 2-way banking;
// the XOR composed with it collapsed reads to 4-way conflicts = the 6.36e7
// SQ_LDS_BANK_CONFLICT). Values/barriers/logic byte-identical to round 9.
// ---------------------------------------------------------------------------
#define ATT_LDS 65280

__global__ __launch_bounds__(512) void attn_topk_fused(
    const float* __restrict__ Qb, const unsigned short* __restrict__ Ks,
    const unsigned short* __restrict__ Vt, float* __restrict__ attn_out,
    float* __restrict__ CTX)
{
    __shared__ __align__(16) char smem[ATT_LDS];
    unsigned short* q_s = (unsigned short*)smem;                   // [3][16][136]
    unsigned short* k_s = (unsigned short*)(smem + 13056);         // [3][64][136]
    float*          red = (float*)smem;                            // [4][16][16]
    unsigned short* wt  = (unsigned short*)(smem + 13056);         // [16][1032]
    unsigned short* vt  = (unsigned short*)(smem + 13056 + 33024); // [128][72]

    const int tid = threadIdx.x;
    const int wv = tid >> 6, lane = tid & 63;
    const int fg = lane >> 4, fc = lane & 15;

    // XCD-chunked bijective remap: 4096 = 8 XCDs x 512
    const int gg = (blockIdx.x & 7) * 512 + ((int)blockIdx.x >> 3);
    const int bh = gg >> 6, qb = gg & 63;
    const int b = bh >> 4, h = bh & 15;
    const int q0 = qb * 16;

    const float* Qg = Qb + (size_t)(b * SS + q0) * DD + h * DKK;
    const unsigned short* Ksg = Ks + (size_t)bh * SS * DKK;
    const unsigned short* Vtg = Vt + (size_t)(h * DKK) * MROWS + b * SS;
    float* aob = attn_out + (size_t)(bh * SS + q0) * SS;

    // ---- stage Q splits (once): 512 units = 16 rows x 32 c4 ----
    {
        int row = tid >> 5, c4 = tid & 31;
        float4 v = *(const float4*)(Qg + (size_t)row * DD + c4 * 4);
        int off = row * 136 + c4 * 4;      // de-XORed
        su4 p1, p2, p3; split4(v, p1, p2, p3);
        *(su4*)&q_s[off] = p1;
        *(su4*)&q_s[2176 + off] = p2;
        *(su4*)&q_s[4352 + off] = p3;
    }
    __syncthreads();

    // ---- persistent A-frags: af[split][ktile-of-my-dhalf] ----
    const int kt0 = (wv >> 2) * 2;   // ktile base: 0 (d 0..63) or 2 (d 64..127)
    su8 af[3][2];
    #pragma unroll
    for (int p = 0; p < 3; ++p)
        #pragma unroll
        for (int kk = 0; kk < 2; ++kk)
            af[p][kk] = *(const su8*)&q_s[p * 2176 + fc * 136 +
                            ((kt0 + kk) * 4 + fg) * 8];           // de-XORed

    // ---- scores over 16 key-tiles of 64 ----
    for (int t = 0; t < 16; ++t) {
        // stage pre-split K tile: pure copies (p = pu>>1, u = pu&1)
        #pragma unroll
        for (int pu = 0; pu < 6; ++pu) {
            const int p = pu >> 1;
            const int rem = tid + 512 * (pu & 1);
            const int row = rem >> 4, c8 = rem & 15;
            su8 v = *(const su8*)(Ksg + p * KPLANE +
                                  (size_t)(t * 64 + row) * DKK + c8 * 8);
            *(su8*)&k_s[p * 8704 + row * 136 + c8 * 8] = v;       // de-XORed
        }
        __syncthreads();

        const int krow = (wv & 3) * 16 + fc;
        su8 bf[3][2];
        #pragma unroll
        for (int p = 0; p < 3; ++p)
            #pragma unroll
            for (int kk = 0; kk < 2; ++kk)
                bf[p][kk] = *(const su8*)&k_s[p * 8704 + krow * 136 +
                                ((kt0 + kk) * 4 + fg) * 8];       // de-XORed

        f32x4 acc = {0.f, 0.f, 0.f, 0.f};
        // passes small->large: (q3,k1),(q1,k3),(q2,k2),(q2,k1),(q1,k2),(q1,k1)
        constexpr int PI[6] = {2, 0, 1, 1, 0, 0};
        constexpr int PJ[6] = {0, 2, 1, 0, 1, 0};
        #pragma unroll
        for (int p = 0; p < 6; ++p)
            #pragma unroll
            for (int kk = 0; kk < 2; ++kk)
                asm volatile("v_mfma_f32_16x16x32_bf16 %0, %1, %2, %0"
                             : "+v"(acc) : "v"(af[PI[p]][kk]), "v"(bf[PJ[p]][kk]));
        asm volatile("s_nop 7\n\ts_nop 7" ::: "memory");

        if (kt0 == 2) {
            #pragma unroll
            for (int j = 0; j < 4; ++j)
                red[(wv & 3) * 256 + (4 * fg + j) * 16 + fc] = acc[j];
        }
        __syncthreads();
        if (kt0 == 0) {
            #pragma unroll
            for (int j = 0; j < 4; ++j) {
                float s = (acc[j] + red[(wv & 3) * 256 + (4 * fg + j) * 16 + fc]) * SCALE;
                aob[(size_t)(4 * fg + j) * SS + t * 64 + (wv & 3) * 16 + fc] = s;
            }
        }
        __syncthreads();  // red safe for next tile; k_s safe to restage
    }
    __syncthreads();  // all scores visible within block

    // ---- selection + softmax params (verified ballot bit-descent), 2 rows ----
    unsigned uv[2][16];
    #pragma unroll
    for (int rr = 0; rr < 2; ++rr) {
        const float* aor = aob + (size_t)(2 * wv + rr) * SS;
        #pragma unroll
        for (int t = 0; t < 16; ++t)
            uv[rr][t] = f2u_ord(aor[t * 64 + lane]);
    }
    unsigned pref[2]; int ecnt[2]; float mrow[2], invz[2], tvexp[2];
    #pragma unroll
    for (int rr = 0; rr < 2; ++rr) {
        unsigned p = 0;
        for (int bit = 31; bit >= 0; --bit) {
            unsigned cand = p | (1u << bit);
            int cnt = 0;
            #pragma unroll
            for (int t = 0; t < 16; ++t)
                cnt += __popcll(__ballot(uv[rr][t] >= cand));
            if (cnt >= KKTOP) p = cand;
        }
        pref[rr] = p;
        int g = 0;
        #pragma unroll
        for (int t = 0; t < 16; ++t)
            g += __popcll(__ballot(uv[rr][t] > p));
        ecnt[rr] = KKTOP - g;

        unsigned um = 0;
        #pragma unroll
        for (int t = 0; t < 16; ++t) um = um > uv[rr][t] ? um : uv[rr][t];
        #pragma unroll
        for (int o = 32; o > 0; o >>= 1) {
            unsigned tv2 = __shfl_down(um, o);
            um = um > tv2 ? um : tv2;
        }
        um = __shfl(um, 0);
        const float m = u2f_ord(um);

        float se = 0.f;
        #pragma unroll
        for (int t = 0; t < 16; ++t)
            if (uv[rr][t] > p) se += expf(u2f_ord(uv[rr][t]) - m);
        #pragma unroll
        for (int o = 32; o > 0; o >>= 1) se += __shfl_down(se, o);
        se = __shfl(se, 0);

        mrow[rr] = m;
        tvexp[rr] = expf(u2f_ord(p) - m);
        invz[rr] = 1.0f / (se + (float)ecnt[rr] * tvexp[rr]);
    }

    // ---- weights: attn_out final + wt bf16 (ties in (t,lane) index order) ----
    #pragma unroll
    for (int rr = 0; rr < 2; ++rr) {
        float* aor = aob + (size_t)(2 * wv + rr) * SS;
        unsigned short* wr = wt + (2 * wv + rr) * 1032;
        int tiesbefore = 0;
        #pragma unroll
        for (int t = 0; t < 16; ++t) {
            const unsigned u = uv[rr][t];
            const bool eq = (u == pref[rr]);
            unsigned long long mask = __ballot(eq);
            float w;
            if (u > pref[rr]) {
                w = expf(u2f_ord(u) - mrow[rr]) * invz[rr];
            } else if (eq) {
                int rank = tiesbefore + __popcll(mask & ((1ull << lane) - 1ull));
                w = (rank < ecnt[rr]) ? tvexp[rr] * invz[rr] : 0.f;
            } else {
                w = 0.f;
            }
            aor[t * 64 + lane] = w;
            wr[t * 64 + lane] = f2bf(w);
            tiesbefore += __popcll(mask);
        }
    }

    // ---- PV: ctx[16][128] = W[16][1024] @ V[1024][128] via bf16 MFMA ----
    f32x4 pacc = {0.f, 0.f, 0.f, 0.f};
    const int pvd = wv * 16 + fc;        // this lane's d column
    for (int t = 0; t < 16; ++t) {
        __syncthreads();   // wt complete (t=0) / prev vt reads done
        #pragma unroll
        for (int u = 0; u < 2; ++u) {
            int rem = tid + 512 * u;
            int d = rem >> 3, kc = rem & 7;
            su8 v = *(const su8*)(Vtg + (size_t)d * MROWS + t * 64 + kc * 8);
            *(su8*)&vt[d * 72 + kc * 8] = v;                      // de-XORed
        }
        __syncthreads();
        #pragma unroll
        for (int kk = 0; kk < 2; ++kk) {
            su8 aw = *(const su8*)&wt[fc * 1032 + t * 64 + (kk * 4 + fg) * 8];
            su8 bv2 = *(const su8*)&vt[pvd * 72 + (kk * 4 + fg) * 8]; // de-XORed
            asm volatile("v_mfma_f32_16x16x32_bf16 %0, %1, %2, %0"
                         : "+v"(pacc) : "v"(aw), "v"(bv2));
        }
    }
    asm volatile("s_nop 7\n\ts_nop 7" ::: "memory");

    #pragma unroll
    for (int j = 0; j < 4; ++j)
        CTX[(size_t)(b * SS + q0 + 4 * fg + j) * DD + h * DKK + pvd] = pacc[j];
}

// ---------------------------------------------------------------------------
extern "C" void kernel_launch(void* const* d_in, const int* in_sizes, int n_in,
                              void* d_out, int out_size, void* d_ws, size_t ws_size,
                              hipStream_t stream)
{
    const float* x  = (const float*)d_in[0];
    const float* Wq = (const float*)d_in[1];
    const float* bq = (const float*)d_in[2];
    const float* Wk = (const float*)d_in[3];
    const float* bk = (const float*)d_in[4];
    const float* Wv = (const float*)d_in[5];
    const float* bv = (const float*)d_in[6];
    const float* Wo = (const float*)d_in[7];
    const float* bo = (const float*)d_in[8];

    float* out      = (float*)d_out;                       // [4,1024,2048]
    float* attn_out = (float*)d_out + (size_t)MROWS * DD;  // [4,16,1024,1024]

    float* ws = (float*)d_ws;
    const size_t PLANE = (size_t)MROWS * DD;   // 8,388,608
    // ws carve (134.2 MB, identical to round-9):
    float* Qb = ws;
    unsigned short* Ksp = (unsigned short*)(ws + PLANE);
    float* CTX = ws + PLANE + PLANE * 3 / 2;
    unsigned short* Vtp = (unsigned short*)(ws + PLANE + PLANE * 3 / 2 + PLANE);

    dim3 gb(MROWS / TM, DD / TN);   // (32,16)
    gemm_nt_f32<<<gb, 256, 0, stream>>>(x, Wq, bq, Qb, MROWS, DD, DD);
    gemm_nt_f32_ksplit<<<gb, 256, 0, stream>>>(x, Wk, bk, Ksp, MROWS, DD, DD);
    gemm_nt_bf16_tv<<<dim3(DD / TM, MROWS / TN), 256, 0, stream>>>(
        Wv, x, bv, Vtp, DD, MROWS, DD);

    attn_topk_fused<<<dim3(BB * HH * (SS / 16)), 512, 0, stream>>>(
        Qb, Ksp, Vtp, attn_out, CTX);

    gemm_nt_bf16<<<gb, 256, 0, stream>>>(CTX, Wo, bo, out, MROWS, DD, DD);
}

// Round 12
// 1082.069 us; speedup vs baseline: 3.6940x; 1.5396x over previous
//
#include <hip/hip_runtime.h>
#include <math.h>

// Problem constants
#define BB 4
#define SS 1024
#define DD 2048
#define HH 16
#define DKK 128
#define KKTOP 307           // int(1024 * 0.3)
#define MROWS (BB * SS)     // 4096
#define KPLANE ((size_t)MROWS * DD)   // elements per K-split plane (8,388,608)
static __device__ __constant__ float SCALE = 0.08838834764831845f; // 1/sqrt(128)

typedef float f32x4 __attribute__((ext_vector_type(4)));
typedef unsigned short su4 __attribute__((ext_vector_type(4)));
typedef unsigned short su8 __attribute__((ext_vector_type(8)));

__device__ __forceinline__ unsigned short f2bf(float x) {   // RNE
    unsigned u = __float_as_uint(x);
    u += 0x7fffu + ((u >> 16) & 1u);
    return (unsigned short)(u >> 16);
}
__device__ __forceinline__ float bf2f(unsigned short b) {
    return __uint_as_float((unsigned)b << 16);
}
__device__ __forceinline__ unsigned f2u_ord(float f) {
    unsigned x = __float_as_uint(f);
    return (x & 0x80000000u) ? ~x : (x | 0x80000000u);
}
__device__ __forceinline__ float u2f_ord(unsigned u) {
    return __uint_as_float((u & 0x80000000u) ? (u & 0x7fffffffu) : ~u);
}
// 3-way bf16 split of fp32 (captures ~24 mantissa bits)
__device__ __forceinline__ void split4(float4 v, su4& a, su4& b, su4& c) {
    float x[4] = {v.x, v.y, v.z, v.w};
    #pragma unroll
    for (int i = 0; i < 4; ++i) {
        unsigned short b1 = f2bf(x[i]);
        float r = x[i] - bf2f(b1);
        unsigned short b2 = f2bf(r);
        float r2 = r - bf2f(b2);
        a[i] = b1; b[i] = b2; c[i] = f2bf(r2);
    }
}
// 2-way bf16 split of fp32 (residual <= 2^-9 |x|)
__device__ __forceinline__ void split2_4(float4 v, su4& a, su4& b) {
    float x[4] = {v.x, v.y, v.z, v.w};
    #pragma unroll
    for (int i = 0; i < 4; ++i) {
        unsigned short b1 = f2bf(x[i]);
        float r = x[i] - bf2f(b1);
        a[i] = b1; b[i] = f2bf(r);
    }
}
__device__ __forceinline__ su8 cat44(su4 a, su4 b) {
    su8 r;
    r[0] = a[0]; r[1] = a[1]; r[2] = a[2]; r[3] = a[3];
    r[4] = b[0]; r[5] = b[1]; r[6] = b[2]; r[7] = b[3];
    return r;
}

#define TM 128
#define TN 128

// ---------------------------------------------------------------------------
// GEMM 3-pass split-bf16 MFMA: C[M,N] = A[M,K]@W[N,K]^T + bias, fp32 out.
// A,W split 2-way during staging; passes (a1b2, a2b1, a1b1) leave only the
// a2b2 term (~2^-18 relative) -> fp32-class accuracy at MFMA rate.
// Frag/D-layout identical to round-6-verified gemm_nt_bf16. Used for Q.
// ---------------------------------------------------------------------------
#define G3LD 40

__global__ __launch_bounds__(256) void gemm_nt_3p(
    const float* __restrict__ A, const float* __restrict__ W,
    const float* __restrict__ bias, float* __restrict__ C,
    int M, int N, int K)
{
    __shared__ unsigned short A1[128][G3LD];
    __shared__ unsigned short A2[128][G3LD];
    __shared__ unsigned short B1[128][G3LD];
    __shared__ unsigned short B2[128][G3LD];

    const int tid = threadIdx.x;
    const int bm = blockIdx.x * 128;
    const int bn = blockIdx.y * 128;
    const int wm = (tid >> 6) & 1;
    const int wn = tid >> 7;
    const int lane = tid & 63;
    const int lrow = tid >> 1;
    const int lcol = (tid & 1) * 16;

    f32x4 acc[4][4];
    #pragma unroll
    for (int i = 0; i < 4; ++i)
        #pragma unroll
        for (int j = 0; j < 4; ++j)
            acc[i][j] = (f32x4){0.f, 0.f, 0.f, 0.f};

    for (int kt = 0; kt < K; kt += 32) {
        __syncthreads();
        {
            const float* Ag = A + (size_t)(bm + lrow) * K + kt + lcol;
            const float* Wg = W + (size_t)(bn + lrow) * K + kt + lcol;
            float4 v0, v1; su4 h0, l0, h1, l1;
            v0 = *(const float4*)(Ag + 0);  v1 = *(const float4*)(Ag + 4);
            split2_4(v0, h0, l0); split2_4(v1, h1, l1);
            *(su8*)&A1[lrow][lcol + 0] = cat44(h0, h1);
            *(su8*)&A2[lrow][lcol + 0] = cat44(l0, l1);
            v0 = *(const float4*)(Ag + 8);  v1 = *(const float4*)(Ag + 12);
            split2_4(v0, h0, l0); split2_4(v1, h1, l1);
            *(su8*)&A1[lrow][lcol + 8] = cat44(h0, h1);
            *(su8*)&A2[lrow][lcol + 8] = cat44(l0, l1);
            v0 = *(const float4*)(Wg + 0);  v1 = *(const float4*)(Wg + 4);
            split2_4(v0, h0, l0); split2_4(v1, h1, l1);
            *(su8*)&B1[lrow][lcol + 0] = cat44(h0, h1);
            *(su8*)&B2[lrow][lcol + 0] = cat44(l0, l1);
            v0 = *(const float4*)(Wg + 8);  v1 = *(const float4*)(Wg + 12);
            split2_4(v0, h0, l0); split2_4(v1, h1, l1);
            *(su8*)&B1[lrow][lcol + 8] = cat44(h0, h1);
            *(su8*)&B2[lrow][lcol + 8] = cat44(l0, l1);
        }
        __syncthreads();

        su8 a1[4], a2[4], b1[4], b2[4];
        #pragma unroll
        for (int f = 0; f < 4; ++f) {
            const int fr = f * 16 + (lane & 15);
            const int fk = (lane >> 4) * 8;
            a1[f] = *(const su8*)&A1[wm * 64 + fr][fk];
            a2[f] = *(const su8*)&A2[wm * 64 + fr][fk];
            b1[f] = *(const su8*)&B1[wn * 64 + fr][fk];
            b2[f] = *(const su8*)&B2[wn * 64 + fr][fk];
        }
        #pragma unroll
        for (int fi = 0; fi < 4; ++fi)
            #pragma unroll
            for (int fj = 0; fj < 4; ++fj) {
                asm volatile("v_mfma_f32_16x16x32_bf16 %0, %1, %2, %0"
                             : "+v"(acc[fi][fj]) : "v"(a1[fi]), "v"(b2[fj]));
                asm volatile("v_mfma_f32_16x16x32_bf16 %0, %1, %2, %0"
                             : "+v"(acc[fi][fj]) : "v"(a2[fi]), "v"(b1[fj]));
                asm volatile("v_mfma_f32_16x16x32_bf16 %0, %1, %2, %0"
                             : "+v"(acc[fi][fj]) : "v"(a1[fi]), "v"(b1[fj]));
            }
    }

    asm volatile("s_nop 7\n\ts_nop 7" ::: "memory");

    #pragma unroll
    for (int fj = 0; fj < 4; ++fj) {
        const int col = bn + wn * 64 + fj * 16 + (lane & 15);
        const float bv = bias[col];
        #pragma unroll
        for (int fi = 0; fi < 4; ++fi) {
            const int r0 = bm + wm * 64 + fi * 16 + (lane >> 4) * 4;
            #pragma unroll
            for (int j = 0; j < 4; ++j)
                C[(size_t)(r0 + j) * N + col] = acc[fi][fj][j] + bv;
        }
    }
}

// ---------------------------------------------------------------------------
// Same 3-pass core, K-split epilogue: writes 3 bf16 split planes
// Ks[p][(b*HH+h)*SS + tok][d]  (col = h*128 + d since N-tile == DKK).
// ---------------------------------------------------------------------------
__global__ __launch_bounds__(256) void gemm_nt_3p_ksplit(
    const float* __restrict__ A, const float* __restrict__ W,
    const float* __restrict__ bias, unsigned short* __restrict__ Ks,
    int M, int N, int K)
{
    __shared__ unsigned short A1[128][G3LD];
    __shared__ unsigned short A2[128][G3LD];
    __shared__ unsigned short B1[128][G3LD];
    __shared__ unsigned short B2[128][G3LD];

    const int tid = threadIdx.x;
    const int bm = blockIdx.x * 128;
    const int bn = blockIdx.y * 128;
    const int wm = (tid >> 6) & 1;
    const int wn = tid >> 7;
    const int lane = tid & 63;
    const int lrow = tid >> 1;
    const int lcol = (tid & 1) * 16;

    f32x4 acc[4][4];
    #pragma unroll
    for (int i = 0; i < 4; ++i)
        #pragma unroll
        for (int j = 0; j < 4; ++j)
            acc[i][j] = (f32x4){0.f, 0.f, 0.f, 0.f};

    for (int kt = 0; kt < K; kt += 32) {
        __syncthreads();
        {
            const float* Ag = A + (size_t)(bm + lrow) * K + kt + lcol;
            const float* Wg = W + (size_t)(bn + lrow) * K + kt + lcol;
            float4 v0, v1; su4 h0, l0, h1, l1;
            v0 = *(const float4*)(Ag + 0);  v1 = *(const float4*)(Ag + 4);
            split2_4(v0, h0, l0); split2_4(v1, h1, l1);
            *(su8*)&A1[lrow][lcol + 0] = cat44(h0, h1);
            *(su8*)&A2[lrow][lcol + 0] = cat44(l0, l1);
            v0 = *(const float4*)(Ag + 8);  v1 = *(const float4*)(Ag + 12);
            split2_4(v0, h0, l0); split2_4(v1, h1, l1);
            *(su8*)&A1[lrow][lcol + 8] = cat44(h0, h1);
            *(su8*)&A2[lrow][lcol + 8] = cat44(l0, l1);
            v0 = *(const float4*)(Wg + 0);  v1 = *(const float4*)(Wg + 4);
            split2_4(v0, h0, l0); split2_4(v1, h1, l1);
            *(su8*)&B1[lrow][lcol + 0] = cat44(h0, h1);
            *(su8*)&B2[lrow][lcol + 0] = cat44(l0, l1);
            v0 = *(const float4*)(Wg + 8);  v1 = *(const float4*)(Wg + 12);
            split2_4(v0, h0, l0); split2_4(v1, h1, l1);
            *(su8*)&B1[lrow][lcol + 8] = cat44(h0, h1);
            *(su8*)&B2[lrow][lcol + 8] = cat44(l0, l1);
        }
        __syncthreads();

        su8 a1[4], a2[4], b1[4], b2[4];
        #pragma unroll
        for (int f = 0; f < 4; ++f) {
            const int fr = f * 16 + (lane & 15);
            const int fk = (lane >> 4) * 8;
            a1[f] = *(const su8*)&A1[wm * 64 + fr][fk];
            a2[f] = *(const su8*)&A2[wm * 64 + fr][fk];
            b1[f] = *(const su8*)&B1[wn * 64 + fr][fk];
            b2[f] = *(const su8*)&B2[wn * 64 + fr][fk];
        }
        #pragma unroll
        for (int fi = 0; fi < 4; ++fi)
            #pragma unroll
            for (int fj = 0; fj < 4; ++fj) {
                asm volatile("v_mfma_f32_16x16x32_bf16 %0, %1, %2, %0"
                             : "+v"(acc[fi][fj]) : "v"(a1[fi]), "v"(b2[fj]));
                asm volatile("v_mfma_f32_16x16x32_bf16 %0, %1, %2, %0"
                             : "+v"(acc[fi][fj]) : "v"(a2[fi]), "v"(b1[fj]));
                asm volatile("v_mfma_f32_16x16x32_bf16 %0, %1, %2, %0"
                             : "+v"(acc[fi][fj]) : "v"(a1[fi]), "v"(b1[fj]));
            }
    }

    asm volatile("s_nop 7\n\ts_nop 7" ::: "memory");

    #pragma unroll
    for (int fj = 0; fj < 4; ++fj) {
        const int col = bn + wn * 64 + fj * 16 + (lane & 15);
        const int h = col >> 7, d = col & (DKK - 1);
        const float bv = bias[col];
        #pragma unroll
        for (int fi = 0; fi < 4; ++fi) {
            const int r0 = bm + wm * 64 + fi * 16 + (lane >> 4) * 4;
            #pragma unroll
            for (int j = 0; j < 4; ++j) {
                const int tok = r0 + j;
                const float val = acc[fi][fj][j] + bv;
                const size_t o = ((size_t)((tok >> 10) * HH + h) * SS
                                  + (tok & (SS - 1))) * DKK + d;
                unsigned short s1 = f2bf(val);
                float r = val - bf2f(s1);
                unsigned short s2 = f2bf(r);
                float r2 = r - bf2f(s2);
                Ks[0 * KPLANE + o] = s1;
                Ks[1 * KPLANE + o] = s2;
                Ks[2 * KPLANE + o] = f2bf(r2);
            }
        }
    }
}

// ---------------------------------------------------------------------------
// GEMM bf16-MFMA (round-6 verified, verbatim): fp32 in/out. Used for O-proj.
// ---------------------------------------------------------------------------
#define GLDA 40

__device__ __forceinline__ su8 pack8(float4 x, float4 y) {
    su8 r;
    r[0] = f2bf(x.x); r[1] = f2bf(x.y); r[2] = f2bf(x.z); r[3] = f2bf(x.w);
    r[4] = f2bf(y.x); r[5] = f2bf(y.y); r[6] = f2bf(y.z); r[7] = f2bf(y.w);
    return r;
}

__global__ __launch_bounds__(256) void gemm_nt_bf16(
    const float* __restrict__ A, const float* __restrict__ W,
    const float* __restrict__ bias, float* __restrict__ C,
    int M, int N, int K)
{
    __shared__ unsigned short Ab[128][GLDA];
    __shared__ unsigned short Bb[128][GLDA];

    const int tid = threadIdx.x;
    const int bm = blockIdx.x * 128;
    const int bn = blockIdx.y * 128;
    const int wm = (tid >> 6) & 1;
    const int wn = tid >> 7;
    const int lane = tid & 63;
    const int lrow = tid >> 1;
    const int lcol = (tid & 1) * 16;

    f32x4 acc[4][4];
    #pragma unroll
    for (int i = 0; i < 4; ++i)
        #pragma unroll
        for (int j = 0; j < 4; ++j)
            acc[i][j] = (f32x4){0.f, 0.f, 0.f, 0.f};

    for (int kt = 0; kt < K; kt += 32) {
        __syncthreads();
        {
            const float* Ag = A + (size_t)(bm + lrow) * K + kt + lcol;
            const float* Wg = W + (size_t)(bn + lrow) * K + kt + lcol;
            float4 a0 = *(const float4*)(Ag + 0);
            float4 a1 = *(const float4*)(Ag + 4);
            float4 a2 = *(const float4*)(Ag + 8);
            float4 a3 = *(const float4*)(Ag + 12);
            *(su8*)&Ab[lrow][lcol + 0] = pack8(a0, a1);
            *(su8*)&Ab[lrow][lcol + 8] = pack8(a2, a3);
            float4 b0 = *(const float4*)(Wg + 0);
            float4 b1 = *(const float4*)(Wg + 4);
            float4 b2 = *(const float4*)(Wg + 8);
            float4 b3 = *(const float4*)(Wg + 12);
            *(su8*)&Bb[lrow][lcol + 0] = pack8(b0, b1);
            *(su8*)&Bb[lrow][lcol + 8] = pack8(b2, b3);
        }
        __syncthreads();

        su8 af[4], bf[4];
        #pragma unroll
        for (int f = 0; f < 4; ++f) {
            af[f] = *(const su8*)&Ab[wm * 64 + f * 16 + (lane & 15)][(lane >> 4) * 8];
            bf[f] = *(const su8*)&Bb[wn * 64 + f * 16 + (lane & 15)][(lane >> 4) * 8];
        }
        #pragma unroll
        for (int fi = 0; fi < 4; ++fi)
            #pragma unroll
            for (int fj = 0; fj < 4; ++fj)
                asm volatile("v_mfma_f32_16x16x32_bf16 %0, %1, %2, %0"
                             : "+v"(acc[fi][fj])
                             : "v"(af[fi]), "v"(bf[fj]));
    }

    asm volatile("s_nop 7\n\ts_nop 7" ::: "memory");

    #pragma unroll
    for (int fj = 0; fj < 4; ++fj) {
        const int col = bn + wn * 64 + fj * 16 + (lane & 15);
        const float bv = bias[col];
        #pragma unroll
        for (int fi = 0; fi < 4; ++fi) {
            const int r0 = bm + wm * 64 + fi * 16 + (lane >> 4) * 4;
            #pragma unroll
            for (int j = 0; j < 4; ++j)
                C[(size_t)(r0 + j) * N + col] = acc[fi][fj][j] + bv;
        }
    }
}

// ---------------------------------------------------------------------------
// GEMM bf16-MFMA, transposed-V variant (round-8 verified, verbatim).
// ---------------------------------------------------------------------------
__global__ __launch_bounds__(256) void gemm_nt_bf16_tv(
    const float* __restrict__ A, const float* __restrict__ W,
    const float* __restrict__ bias, unsigned short* __restrict__ Cb,
    int M, int N, int K)
{
    __shared__ unsigned short Ab[128][GLDA];
    __shared__ unsigned short Bb[128][GLDA];

    const int tid = threadIdx.x;
    const int bm = blockIdx.x * 128;
    const int bn = blockIdx.y * 128;
    const int wm = (tid >> 6) & 1;
    const int wn = tid >> 7;
    const int lane = tid & 63;
    const int lrow = tid >> 1;
    const int lcol = (tid & 1) * 16;

    f32x4 acc[4][4];
    #pragma unroll
    for (int i = 0; i < 4; ++i)
        #pragma unroll
        for (int j = 0; j < 4; ++j)
            acc[i][j] = (f32x4){0.f, 0.f, 0.f, 0.f};

    for (int kt = 0; kt < K; kt += 32) {
        __syncthreads();
        {
            const float* Ag = A + (size_t)(bm + lrow) * K + kt + lcol;
            const float* Wg = W + (size_t)(bn + lrow) * K + kt + lcol;
            float4 a0 = *(const float4*)(Ag + 0);
            float4 a1 = *(const float4*)(Ag + 4);
            float4 a2 = *(const float4*)(Ag + 8);
            float4 a3 = *(const float4*)(Ag + 12);
            *(su8*)&Ab[lrow][lcol + 0] = pack8(a0, a1);
            *(su8*)&Ab[lrow][lcol + 8] = pack8(a2, a3);
            float4 b0 = *(const float4*)(Wg + 0);
            float4 b1 = *(const float4*)(Wg + 4);
            float4 b2 = *(const float4*)(Wg + 8);
            float4 b3 = *(const float4*)(Wg + 12);
            *(su8*)&Bb[lrow][lcol + 0] = pack8(b0, b1);
            *(su8*)&Bb[lrow][lcol + 8] = pack8(b2, b3);
        }
        __syncthreads();

        su8 af[4], bf[4];
        #pragma unroll
        for (int f = 0; f < 4; ++f) {
            af[f] = *(const su8*)&Ab[wm * 64 + f * 16 + (lane & 15)][(lane >> 4) * 8];
            bf[f] = *(const su8*)&Bb[wn * 64 + f * 16 + (lane & 15)][(lane >> 4) * 8];
        }
        #pragma unroll
        for (int fi = 0; fi < 4; ++fi)
            #pragma unroll
            for (int fj = 0; fj < 4; ++fj)
                asm volatile("v_mfma_f32_16x16x32_bf16 %0, %1, %2, %0"
                             : "+v"(acc[fi][fj])
                             : "v"(af[fi]), "v"(bf[fj]));
    }

    asm volatile("s_nop 7\n\ts_nop 7" ::: "memory");

    #pragma unroll
    for (int fj = 0; fj < 4; ++fj) {
        const int col = bn + wn * 64 + fj * 16 + (lane & 15);
        #pragma unroll
        for (int fi = 0; fi < 4; ++fi) {
            const int r0 = bm + wm * 64 + fi * 16 + (lane >> 4) * 4;
            #pragma unroll
            for (int j = 0; j < 4; ++j) {
                float v = acc[fi][fj][j] + bias[r0 + j];
                Cb[(size_t)(r0 + j) * N + col] = f2bf(v);
            }
        }
    }
}

// ---------------------------------------------------------------------------
// Fused attn — round-11 verified kernel, verbatim.
// ---------------------------------------------------------------------------
#define ATT_LDS 65280

__global__ __launch_bounds__(512) void attn_topk_fused(
    const float* __restrict__ Qb, const unsigned short* __restrict__ Ks,
    const unsigned short* __restrict__ Vt, float* __restrict__ attn_out,
    float* __restrict__ CTX)
{
    __shared__ __align__(16) char smem[ATT_LDS];
    unsigned short* q_s = (unsigned short*)smem;                   // [3][16][136]
    unsigned short* k_s = (unsigned short*)(smem + 13056);         // [3][64][136]
    float*          red = (float*)smem;                            // [4][16][16]
    unsigned short* wt  = (unsigned short*)(smem + 13056);         // [16][1032]
    unsigned short* vt  = (unsigned short*)(smem + 13056 + 33024); // [128][72]

    const int tid = threadIdx.x;
    const int wv = tid >> 6, lane = tid & 63;
    const int fg = lane >> 4, fc = lane & 15;

    // XCD-chunked bijective remap: 4096 = 8 XCDs x 512
    const int gg = (blockIdx.x & 7) * 512 + ((int)blockIdx.x >> 3);
    const int bh = gg >> 6, qb = gg & 63;
    const int b = bh >> 4, h = bh & 15;
    const int q0 = qb * 16;

    const float* Qg = Qb + (size_t)(b * SS + q0) * DD + h * DKK;
    const unsigned short* Ksg = Ks + (size_t)bh * SS * DKK;
    const unsigned short* Vtg = Vt + (size_t)(h * DKK) * MROWS + b * SS;
    float* aob = attn_out + (size_t)(bh * SS + q0) * SS;

    // ---- stage Q splits (once): 512 units = 16 rows x 32 c4 ----
    {
        int row = tid >> 5, c4 = tid & 31;
        float4 v = *(const float4*)(Qg + (size_t)row * DD + c4 * 4);
        int off = row * 136 + c4 * 4;
        su4 p1, p2, p3; split4(v, p1, p2, p3);
        *(su4*)&q_s[off] = p1;
        *(su4*)&q_s[2176 + off] = p2;
        *(su4*)&q_s[4352 + off] = p3;
    }
    __syncthreads();

    // ---- persistent A-frags: af[split][ktile-of-my-dhalf] ----
    const int kt0 = (wv >> 2) * 2;   // ktile base: 0 (d 0..63) or 2 (d 64..127)
    su8 af[3][2];
    #pragma unroll
    for (int p = 0; p < 3; ++p)
        #pragma unroll
        for (int kk = 0; kk < 2; ++kk)
            af[p][kk] = *(const su8*)&q_s[p * 2176 + fc * 136 +
                            ((kt0 + kk) * 4 + fg) * 8];

    // ---- scores over 16 key-tiles of 64 ----
    for (int t = 0; t < 16; ++t) {
        #pragma unroll
        for (int pu = 0; pu < 6; ++pu) {
            const int p = pu >> 1;
            const int rem = tid + 512 * (pu & 1);
            const int row = rem >> 4, c8 = rem & 15;
            su8 v = *(const su8*)(Ksg + p * KPLANE +
                                  (size_t)(t * 64 + row) * DKK + c8 * 8);
            *(su8*)&k_s[p * 8704 + row * 136 + c8 * 8] = v;
        }
        __syncthreads();

        const int krow = (wv & 3) * 16 + fc;
        su8 bf[3][2];
        #pragma unroll
        for (int p = 0; p < 3; ++p)
            #pragma unroll
            for (int kk = 0; kk < 2; ++kk)
                bf[p][kk] = *(const su8*)&k_s[p * 8704 + krow * 136 +
                                ((kt0 + kk) * 4 + fg) * 8];

        f32x4 acc = {0.f, 0.f, 0.f, 0.f};
        // passes small->large: (q3,k1),(q1,k3),(q2,k2),(q2,k1),(q1,k2),(q1,k1)
        constexpr int PI[6] = {2, 0, 1, 1, 0, 0};
        constexpr int PJ[6] = {0, 2, 1, 0, 1, 0};
        #pragma unroll
        for (int p = 0; p < 6; ++p)
            #pragma unroll
            for (int kk = 0; kk < 2; ++kk)
                asm volatile("v_mfma_f32_16x16x32_bf16 %0, %1, %2, %0"
                             : "+v"(acc) : "v"(af[PI[p]][kk]), "v"(bf[PJ[p]][kk]));
        asm volatile("s_nop 7\n\ts_nop 7" ::: "memory");

        if (kt0 == 2) {
            #pragma unroll
            for (int j = 0; j < 4; ++j)
                red[(wv & 3) * 256 + (4 * fg + j) * 16 + fc] = acc[j];
        }
        __syncthreads();
        if (kt0 == 0) {
            #pragma unroll
            for (int j = 0; j < 4; ++j) {
                float s = (acc[j] + red[(wv & 3) * 256 + (4 * fg + j) * 16 + fc]) * SCALE;
                aob[(size_t)(4 * fg + j) * SS + t * 64 + (wv & 3) * 16 + fc] = s;
            }
        }
        __syncthreads();  // red safe for next tile; k_s safe to restage
    }
    __syncthreads();  // all scores visible within block

    // ---- selection + softmax params (verified ballot bit-descent), 2 rows ----
    unsigned uv[2][16];
    #pragma unroll
    for (int rr = 0; rr < 2; ++rr) {
        const float* aor = aob + (size_t)(2 * wv + rr) * SS;
        #pragma unroll
        for (int t = 0; t < 16; ++t)
            uv[rr][t] = f2u_ord(aor[t * 64 + lane]);
    }
    unsigned pref[2]; int ecnt[2]; float mrow[2], invz[2], tvexp[2];
    #pragma unroll
    for (int rr = 0; rr < 2; ++rr) {
        unsigned p = 0;
        for (int bit = 31; bit >= 0; --bit) {
            unsigned cand = p | (1u << bit);
            int cnt = 0;
            #pragma unroll
            for (int t = 0; t < 16; ++t)
                cnt += __popcll(__ballot(uv[rr][t] >= cand));
            if (cnt >= KKTOP) p = cand;
        }
        pref[rr] = p;
        int g = 0;
        #pragma unroll
        for (int t = 0; t < 16; ++t)
            g += __popcll(__ballot(uv[rr][t] > p));
        ecnt[rr] = KKTOP - g;

        unsigned um = 0;
        #pragma unroll
        for (int t = 0; t < 16; ++t) um = um > uv[rr][t] ? um : uv[rr][t];
        #pragma unroll
        for (int o = 32; o > 0; o >>= 1) {
            unsigned tv2 = __shfl_down(um, o);
            um = um > tv2 ? um : tv2;
        }
        um = __shfl(um, 0);
        const float m = u2f_ord(um);

        float se = 0.f;
        #pragma unroll
        for (int t = 0; t < 16; ++t)
            if (uv[rr][t] > p) se += expf(u2f_ord(uv[rr][t]) - m);
        #pragma unroll
        for (int o = 32; o > 0; o >>= 1) se += __shfl_down(se, o);
        se = __shfl(se, 0);

        mrow[rr] = m;
        tvexp[rr] = expf(u2f_ord(p) - m);
        invz[rr] = 1.0f / (se + (float)ecnt[rr] * tvexp[rr]);
    }

    // ---- weights: attn_out final + wt bf16 (ties in (t,lane) index order) ----
    #pragma unroll
    for (int rr = 0; rr < 2; ++rr) {
        float* aor = aob + (size_t)(2 * wv + rr) * SS;
        unsigned short* wr = wt + (2 * wv + rr) * 1032;
        int tiesbefore = 0;
        #pragma unroll
        for (int t = 0; t < 16; ++t) {
            const unsigned u = uv[rr][t];
            const bool eq = (u == pref[rr]);
            unsigned long long mask = __ballot(eq);
            float w;
            if (u > pref[rr]) {
                w = expf(u2f_ord(u) - mrow[rr]) * invz[rr];
            } else if (eq) {
                int rank = tiesbefore + __popcll(mask & ((1ull << lane) - 1ull));
                w = (rank < ecnt[rr]) ? tvexp[rr] * invz[rr] : 0.f;
            } else {
                w = 0.f;
            }
            aor[t * 64 + lane] = w;
            wr[t * 64 + lane] = f2bf(w);
            tiesbefore += __popcll(mask);
        }
    }

    // ---- PV: ctx[16][128] = W[16][1024] @ V[1024][128] via bf16 MFMA ----
    f32x4 pacc = {0.f, 0.f, 0.f, 0.f};
    const int pvd = wv * 16 + fc;        // this lane's d column
    for (int t = 0; t < 16; ++t) {
        __syncthreads();   // wt complete (t=0) / prev vt reads done
        #pragma unroll
        for (int u = 0; u < 2; ++u) {
            int rem = tid + 512 * u;
            int d = rem >> 3, kc = rem & 7;
            su8 v = *(const su8*)(Vtg + (size_t)d * MROWS + t * 64 + kc * 8);
            *(su8*)&vt[d * 72 + kc * 8] = v;
        }
        __syncthreads();
        #pragma unroll
        for (int kk = 0; kk < 2; ++kk) {
            su8 aw = *(const su8*)&wt[fc * 1032 + t * 64 + (kk * 4 + fg) * 8];
            su8 bv2 = *(const su8*)&vt[pvd * 72 + (kk * 4 + fg) * 8];
            asm volatile("v_mfma_f32_16x16x32_bf16 %0, %1, %2, %0"
                         : "+v"(pacc) : "v"(aw), "v"(bv2));
        }
    }
    asm volatile("s_nop 7\n\ts_nop 7" ::: "memory");

    #pragma unroll
    for (int j = 0; j < 4; ++j)
        CTX[(size_t)(b * SS + q0 + 4 * fg + j) * DD + h * DKK + pvd] = pacc[j];
}

// ---------------------------------------------------------------------------
extern "C" void kernel_launch(void* const* d_in, const int* in_sizes, int n_in,
                              void* d_out, int out_size, void* d_ws, size_t ws_size,
                              hipStream_t stream)
{
    const float* x  = (const float*)d_in[0];
    const float* Wq = (const float*)d_in[1];
    const float* bq = (const float*)d_in[2];
    const float* Wk = (const float*)d_in[3];
    const float* bk = (const float*)d_in[4];
    const float* Wv = (const float*)d_in[5];
    const float* bv = (const float*)d_in[6];
    const float* Wo = (const float*)d_in[7];
    const float* bo = (const float*)d_in[8];

    float* out      = (float*)d_out;                       // [4,1024,2048]
    float* attn_out = (float*)d_out + (size_t)MROWS * DD;  // [4,16,1024,1024]

    float* ws = (float*)d_ws;
    const size_t PLANE = (size_t)MROWS * DD;   // 8,388,608
    // ws carve (134.2 MB, identical to round-9/11):
    float* Qb = ws;
    unsigned short* Ksp = (unsigned short*)(ws + PLANE);
    float* CTX = ws + PLANE + PLANE * 3 / 2;
    unsigned short* Vtp = (unsigned short*)(ws + PLANE + PLANE * 3 / 2 + PLANE);

    dim3 gb(MROWS / TM, DD / TN);   // (32,16)
    gemm_nt_3p<<<gb, 256, 0, stream>>>(x, Wq, bq, Qb, MROWS, DD, DD);
    gemm_nt_3p_ksplit<<<gb, 256, 0, stream>>>(x, Wk, bk, Ksp, MROWS, DD, DD);
    gemm_nt_bf16_tv<<<dim3(DD / TM, MROWS / TN), 256, 0, stream>>>(
        Wv, x, bv, Vtp, DD, MROWS, DD);

    attn_topk_fused<<<dim3(BB * HH * (SS / 16)), 512, 0, stream>>>(
        Qb, Ksp, Vtp, attn_out, CTX);

    gemm_nt_bf16<<<gb, 256, 0, stream>>>(CTX, Wo, bo, out, MROWS, DD, DD);
}

// Round 13
// 983.527 us; speedup vs baseline: 4.0641x; 1.1002x over previous
//
#include <hip/hip_runtime.h>
#include <math.h>

// Problem constants
#define BB 4
#define SS 1024
#define DD 2048
#define HH 16
#define DKK 128
#define KKTOP 307           // int(1024 * 0.3)
#define MROWS (BB * SS)     // 4096
#define KPLANE ((size_t)MROWS * DD)   // elements per K-split plane (8,388,608)
static __device__ __constant__ float SCALE = 0.08838834764831845f; // 1/sqrt(128)

typedef float f32x4 __attribute__((ext_vector_type(4)));
typedef unsigned short su4 __attribute__((ext_vector_type(4)));
typedef unsigned short su8 __attribute__((ext_vector_type(8)));

__device__ __forceinline__ unsigned short f2bf(float x) {   // RNE
    unsigned u = __float_as_uint(x);
    u += 0x7fffu + ((u >> 16) & 1u);
    return (unsigned short)(u >> 16);
}
__device__ __forceinline__ float bf2f(unsigned short b) {
    return __uint_as_float((unsigned)b << 16);
}
__device__ __forceinline__ unsigned f2u_ord(float f) {
    unsigned x = __float_as_uint(f);
    return (x & 0x80000000u) ? ~x : (x | 0x80000000u);
}
__device__ __forceinline__ float u2f_ord(unsigned u) {
    return __uint_as_float((u & 0x80000000u) ? (u & 0x7fffffffu) : ~u);
}
// 3-way bf16 split of fp32 (captures ~24 mantissa bits)
__device__ __forceinline__ void split4(float4 v, su4& a, su4& b, su4& c) {
    float x[4] = {v.x, v.y, v.z, v.w};
    #pragma unroll
    for (int i = 0; i < 4; ++i) {
        unsigned short b1 = f2bf(x[i]);
        float r = x[i] - bf2f(b1);
        unsigned short b2 = f2bf(r);
        float r2 = r - bf2f(b2);
        a[i] = b1; b[i] = b2; c[i] = f2bf(r2);
    }
}
// 2-way bf16 split of fp32 (residual <= 2^-9 |x|)
__device__ __forceinline__ void split2_4(float4 v, su4& a, su4& b) {
    float x[4] = {v.x, v.y, v.z, v.w};
    #pragma unroll
    for (int i = 0; i < 4; ++i) {
        unsigned short b1 = f2bf(x[i]);
        float r = x[i] - bf2f(b1);
        a[i] = b1; b[i] = f2bf(r);
    }
}
__device__ __forceinline__ su8 cat44(su4 a, su4 b) {
    su8 r;
    r[0] = a[0]; r[1] = a[1]; r[2] = a[2]; r[3] = a[3];
    r[4] = b[0]; r[5] = b[1]; r[6] = b[2]; r[7] = b[3];
    return r;
}

#define TM 128
#define TN 128

// ---------------------------------------------------------------------------
// GEMM 3-pass split-bf16 MFMA (round-12 verified, verbatim). Used for Q.
// ---------------------------------------------------------------------------
#define G3LD 40

__global__ __launch_bounds__(256) void gemm_nt_3p(
    const float* __restrict__ A, const float* __restrict__ W,
    const float* __restrict__ bias, float* __restrict__ C,
    int M, int N, int K)
{
    __shared__ unsigned short A1[128][G3LD];
    __shared__ unsigned short A2[128][G3LD];
    __shared__ unsigned short B1[128][G3LD];
    __shared__ unsigned short B2[128][G3LD];

    const int tid = threadIdx.x;
    const int bm = blockIdx.x * 128;
    const int bn = blockIdx.y * 128;
    const int wm = (tid >> 6) & 1;
    const int wn = tid >> 7;
    const int lane = tid & 63;
    const int lrow = tid >> 1;
    const int lcol = (tid & 1) * 16;

    f32x4 acc[4][4];
    #pragma unroll
    for (int i = 0; i < 4; ++i)
        #pragma unroll
        for (int j = 0; j < 4; ++j)
            acc[i][j] = (f32x4){0.f, 0.f, 0.f, 0.f};

    for (int kt = 0; kt < K; kt += 32) {
        __syncthreads();
        {
            const float* Ag = A + (size_t)(bm + lrow) * K + kt + lcol;
            const float* Wg = W + (size_t)(bn + lrow) * K + kt + lcol;
            float4 v0, v1; su4 h0, l0, h1, l1;
            v0 = *(const float4*)(Ag + 0);  v1 = *(const float4*)(Ag + 4);
            split2_4(v0, h0, l0); split2_4(v1, h1, l1);
            *(su8*)&A1[lrow][lcol + 0] = cat44(h0, h1);
            *(su8*)&A2[lrow][lcol + 0] = cat44(l0, l1);
            v0 = *(const float4*)(Ag + 8);  v1 = *(const float4*)(Ag + 12);
            split2_4(v0, h0, l0); split2_4(v1, h1, l1);
            *(su8*)&A1[lrow][lcol + 8] = cat44(h0, h1);
            *(su8*)&A2[lrow][lcol + 8] = cat44(l0, l1);
            v0 = *(const float4*)(Wg + 0);  v1 = *(const float4*)(Wg + 4);
            split2_4(v0, h0, l0); split2_4(v1, h1, l1);
            *(su8*)&B1[lrow][lcol + 0] = cat44(h0, h1);
            *(su8*)&B2[lrow][lcol + 0] = cat44(l0, l1);
            v0 = *(const float4*)(Wg + 8);  v1 = *(const float4*)(Wg + 12);
            split2_4(v0, h0, l0); split2_4(v1, h1, l1);
            *(su8*)&B1[lrow][lcol + 8] = cat44(h0, h1);
            *(su8*)&B2[lrow][lcol + 8] = cat44(l0, l1);
        }
        __syncthreads();

        su8 a1[4], a2[4], b1[4], b2[4];
        #pragma unroll
        for (int f = 0; f < 4; ++f) {
            const int fr = f * 16 + (lane & 15);
            const int fk = (lane >> 4) * 8;
            a1[f] = *(const su8*)&A1[wm * 64 + fr][fk];
            a2[f] = *(const su8*)&A2[wm * 64 + fr][fk];
            b1[f] = *(const su8*)&B1[wn * 64 + fr][fk];
            b2[f] = *(const su8*)&B2[wn * 64 + fr][fk];
        }
        #pragma unroll
        for (int fi = 0; fi < 4; ++fi)
            #pragma unroll
            for (int fj = 0; fj < 4; ++fj) {
                asm volatile("v_mfma_f32_16x16x32_bf16 %0, %1, %2, %0"
                             : "+v"(acc[fi][fj]) : "v"(a1[fi]), "v"(b2[fj]));
                asm volatile("v_mfma_f32_16x16x32_bf16 %0, %1, %2, %0"
                             : "+v"(acc[fi][fj]) : "v"(a2[fi]), "v"(b1[fj]));
                asm volatile("v_mfma_f32_16x16x32_bf16 %0, %1, %2, %0"
                             : "+v"(acc[fi][fj]) : "v"(a1[fi]), "v"(b1[fj]));
            }
    }

    asm volatile("s_nop 7\n\ts_nop 7" ::: "memory");

    #pragma unroll
    for (int fj = 0; fj < 4; ++fj) {
        const int col = bn + wn * 64 + fj * 16 + (lane & 15);
        const float bv = bias[col];
        #pragma unroll
        for (int fi = 0; fi < 4; ++fi) {
            const int r0 = bm + wm * 64 + fi * 16 + (lane >> 4) * 4;
            #pragma unroll
            for (int j = 0; j < 4; ++j)
                C[(size_t)(r0 + j) * N + col] = acc[fi][fj][j] + bv;
        }
    }
}

// ---------------------------------------------------------------------------
// Same 3-pass core, K-split epilogue (round-12 verified, verbatim).
// ---------------------------------------------------------------------------
__global__ __launch_bounds__(256) void gemm_nt_3p_ksplit(
    const float* __restrict__ A, const float* __restrict__ W,
    const float* __restrict__ bias, unsigned short* __restrict__ Ks,
    int M, int N, int K)
{
    __shared__ unsigned short A1[128][G3LD];
    __shared__ unsigned short A2[128][G3LD];
    __shared__ unsigned short B1[128][G3LD];
    __shared__ unsigned short B2[128][G3LD];

    const int tid = threadIdx.x;
    const int bm = blockIdx.x * 128;
    const int bn = blockIdx.y * 128;
    const int wm = (tid >> 6) & 1;
    const int wn = tid >> 7;
    const int lane = tid & 63;
    const int lrow = tid >> 1;
    const int lcol = (tid & 1) * 16;

    f32x4 acc[4][4];
    #pragma unroll
    for (int i = 0; i < 4; ++i)
        #pragma unroll
        for (int j = 0; j < 4; ++j)
            acc[i][j] = (f32x4){0.f, 0.f, 0.f, 0.f};

    for (int kt = 0; kt < K; kt += 32) {
        __syncthreads();
        {
            const float* Ag = A + (size_t)(bm + lrow) * K + kt + lcol;
            const float* Wg = W + (size_t)(bn + lrow) * K + kt + lcol;
            float4 v0, v1; su4 h0, l0, h1, l1;
            v0 = *(const float4*)(Ag + 0);  v1 = *(const float4*)(Ag + 4);
            split2_4(v0, h0, l0); split2_4(v1, h1, l1);
            *(su8*)&A1[lrow][lcol + 0] = cat44(h0, h1);
            *(su8*)&A2[lrow][lcol + 0] = cat44(l0, l1);
            v0 = *(const float4*)(Ag + 8);  v1 = *(const float4*)(Ag + 12);
            split2_4(v0, h0, l0); split2_4(v1, h1, l1);
            *(su8*)&A1[lrow][lcol + 8] = cat44(h0, h1);
            *(su8*)&A2[lrow][lcol + 8] = cat44(l0, l1);
            v0 = *(const float4*)(Wg + 0);  v1 = *(const float4*)(Wg + 4);
            split2_4(v0, h0, l0); split2_4(v1, h1, l1);
            *(su8*)&B1[lrow][lcol + 0] = cat44(h0, h1);
            *(su8*)&B2[lrow][lcol + 0] = cat44(l0, l1);
            v0 = *(const float4*)(Wg + 8);  v1 = *(const float4*)(Wg + 12);
            split2_4(v0, h0, l0); split2_4(v1, h1, l1);
            *(su8*)&B1[lrow][lcol + 8] = cat44(h0, h1);
            *(su8*)&B2[lrow][lcol + 8] = cat44(l0, l1);
        }
        __syncthreads();

        su8 a1[4], a2[4], b1[4], b2[4];
        #pragma unroll
        for (int f = 0; f < 4; ++f) {
            const int fr = f * 16 + (lane & 15);
            const int fk = (lane >> 4) * 8;
            a1[f] = *(const su8*)&A1[wm * 64 + fr][fk];
            a2[f] = *(const su8*)&A2[wm * 64 + fr][fk];
            b1[f] = *(const su8*)&B1[wn * 64 + fr][fk];
            b2[f] = *(const su8*)&B2[wn * 64 + fr][fk];
        }
        #pragma unroll
        for (int fi = 0; fi < 4; ++fi)
            #pragma unroll
            for (int fj = 0; fj < 4; ++fj) {
                asm volatile("v_mfma_f32_16x16x32_bf16 %0, %1, %2, %0"
                             : "+v"(acc[fi][fj]) : "v"(a1[fi]), "v"(b2[fj]));
                asm volatile("v_mfma_f32_16x16x32_bf16 %0, %1, %2, %0"
                             : "+v"(acc[fi][fj]) : "v"(a2[fi]), "v"(b1[fj]));
                asm volatile("v_mfma_f32_16x16x32_bf16 %0, %1, %2, %0"
                             : "+v"(acc[fi][fj]) : "v"(a1[fi]), "v"(b1[fj]));
            }
    }

    asm volatile("s_nop 7\n\ts_nop 7" ::: "memory");

    #pragma unroll
    for (int fj = 0; fj < 4; ++fj) {
        const int col = bn + wn * 64 + fj * 16 + (lane & 15);
        const int h = col >> 7, d = col & (DKK - 1);
        const float bv = bias[col];
        #pragma unroll
        for (int fi = 0; fi < 4; ++fi) {
            const int r0 = bm + wm * 64 + fi * 16 + (lane >> 4) * 4;
            #pragma unroll
            for (int j = 0; j < 4; ++j) {
                const int tok = r0 + j;
                const float val = acc[fi][fj][j] + bv;
                const size_t o = ((size_t)((tok >> 10) * HH + h) * SS
                                  + (tok & (SS - 1))) * DKK + d;
                unsigned short s1 = f2bf(val);
                float r = val - bf2f(s1);
                unsigned short s2 = f2bf(r);
                float r2 = r - bf2f(s2);
                Ks[0 * KPLANE + o] = s1;
                Ks[1 * KPLANE + o] = s2;
                Ks[2 * KPLANE + o] = f2bf(r2);
            }
        }
    }
}

// ---------------------------------------------------------------------------
// GEMM bf16-MFMA (round-6 verified, verbatim): fp32 in/out. Used for O-proj.
// ---------------------------------------------------------------------------
#define GLDA 40

__device__ __forceinline__ su8 pack8(float4 x, float4 y) {
    su8 r;
    r[0] = f2bf(x.x); r[1] = f2bf(x.y); r[2] = f2bf(x.z); r[3] = f2bf(x.w);
    r[4] = f2bf(y.x); r[5] = f2bf(y.y); r[6] = f2bf(y.z); r[7] = f2bf(y.w);
    return r;
}

__global__ __launch_bounds__(256) void gemm_nt_bf16(
    const float* __restrict__ A, const float* __restrict__ W,
    const float* __restrict__ bias, float* __restrict__ C,
    int M, int N, int K)
{
    __shared__ unsigned short Ab[128][GLDA];
    __shared__ unsigned short Bb[128][GLDA];

    const int tid = threadIdx.x;
    const int bm = blockIdx.x * 128;
    const int bn = blockIdx.y * 128;
    const int wm = (tid >> 6) & 1;
    const int wn = tid >> 7;
    const int lane = tid & 63;
    const int lrow = tid >> 1;
    const int lcol = (tid & 1) * 16;

    f32x4 acc[4][4];
    #pragma unroll
    for (int i = 0; i < 4; ++i)
        #pragma unroll
        for (int j = 0; j < 4; ++j)
            acc[i][j] = (f32x4){0.f, 0.f, 0.f, 0.f};

    for (int kt = 0; kt < K; kt += 32) {
        __syncthreads();
        {
            const float* Ag = A + (size_t)(bm + lrow) * K + kt + lcol;
            const float* Wg = W + (size_t)(bn + lrow) * K + kt + lcol;
            float4 a0 = *(const float4*)(Ag + 0);
            float4 a1 = *(const float4*)(Ag + 4);
            float4 a2 = *(const float4*)(Ag + 8);
            float4 a3 = *(const float4*)(Ag + 12);
            *(su8*)&Ab[lrow][lcol + 0] = pack8(a0, a1);
            *(su8*)&Ab[lrow][lcol + 8] = pack8(a2, a3);
            float4 b0 = *(const float4*)(Wg + 0);
            float4 b1 = *(const float4*)(Wg + 4);
            float4 b2 = *(const float4*)(Wg + 8);
            float4 b3 = *(const float4*)(Wg + 12);
            *(su8*)&Bb[lrow][lcol + 0] = pack8(b0, b1);
            *(su8*)&Bb[lrow][lcol + 8] = pack8(b2, b3);
        }
        __syncthreads();

        su8 af[4], bf[4];
        #pragma unroll
        for (int f = 0; f < 4; ++f) {
            af[f] = *(const su8*)&Ab[wm * 64 + f * 16 + (lane & 15)][(lane >> 4) * 8];
            bf[f] = *(const su8*)&Bb[wn * 64 + f * 16 + (lane & 15)][(lane >> 4) * 8];
        }
        #pragma unroll
        for (int fi = 0; fi < 4; ++fi)
            #pragma unroll
            for (int fj = 0; fj < 4; ++fj)
                asm volatile("v_mfma_f32_16x16x32_bf16 %0, %1, %2, %0"
                             : "+v"(acc[fi][fj])
                             : "v"(af[fi]), "v"(bf[fj]));
    }

    asm volatile("s_nop 7\n\ts_nop 7" ::: "memory");

    #pragma unroll
    for (int fj = 0; fj < 4; ++fj) {
        const int col = bn + wn * 64 + fj * 16 + (lane & 15);
        const float bv = bias[col];
        #pragma unroll
        for (int fi = 0; fi < 4; ++fi) {
            const int r0 = bm + wm * 64 + fi * 16 + (lane >> 4) * 4;
            #pragma unroll
            for (int j = 0; j < 4; ++j)
                C[(size_t)(r0 + j) * N + col] = acc[fi][fj][j] + bv;
        }
    }
}

// ---------------------------------------------------------------------------
// GEMM bf16-MFMA, transposed-V variant (round-8 verified, verbatim).
// ---------------------------------------------------------------------------
__global__ __launch_bounds__(256) void gemm_nt_bf16_tv(
    const float* __restrict__ A, const float* __restrict__ W,
    const float* __restrict__ bias, unsigned short* __restrict__ Cb,
    int M, int N, int K)
{
    __shared__ unsigned short Ab[128][GLDA];
    __shared__ unsigned short Bb[128][GLDA];

    const int tid = threadIdx.x;
    const int bm = blockIdx.x * 128;
    const int bn = blockIdx.y * 128;
    const int wm = (tid >> 6) & 1;
    const int wn = tid >> 7;
    const int lane = tid & 63;
    const int lrow = tid >> 1;
    const int lcol = (tid & 1) * 16;

    f32x4 acc[4][4];
    #pragma unroll
    for (int i = 0; i < 4; ++i)
        #pragma unroll
        for (int j = 0; j < 4; ++j)
            acc[i][j] = (f32x4){0.f, 0.f, 0.f, 0.f};

    for (int kt = 0; kt < K; kt += 32) {
        __syncthreads();
        {
            const float* Ag = A + (size_t)(bm + lrow) * K + kt + lcol;
            const float* Wg = W + (size_t)(bn + lrow) * K + kt + lcol;
            float4 a0 = *(const float4*)(Ag + 0);
            float4 a1 = *(const float4*)(Ag + 4);
            float4 a2 = *(const float4*)(Ag + 8);
            float4 a3 = *(const float4*)(Ag + 12);
            *(su8*)&Ab[lrow][lcol + 0] = pack8(a0, a1);
            *(su8*)&Ab[lrow][lcol + 8] = pack8(a2, a3);
            float4 b0 = *(const float4*)(Wg + 0);
            float4 b1 = *(const float4*)(Wg + 4);
            float4 b2 = *(const float4*)(Wg + 8);
            float4 b3 = *(const float4*)(Wg + 12);
            *(su8*)&Bb[lrow][lcol + 0] = pack8(b0, b1);
            *(su8*)&Bb[lrow][lcol + 8] = pack8(b2, b3);
        }
        __syncthreads();

        su8 af[4], bf[4];
        #pragma unroll
        for (int f = 0; f < 4; ++f) {
            af[f] = *(const su8*)&Ab[wm * 64 + f * 16 + (lane & 15)][(lane >> 4) * 8];
            bf[f] = *(const su8*)&Bb[wn * 64 + f * 16 + (lane & 15)][(lane >> 4) * 8];
        }
        #pragma unroll
        for (int fi = 0; fi < 4; ++fi)
            #pragma unroll
            for (int fj = 0; fj < 4; ++fj)
                asm volatile("v_mfma_f32_16x16x32_bf16 %0, %1, %2, %0"
                             : "+v"(acc[fi][fj])
                             : "v"(af[fi]), "v"(bf[fj]));
    }

    asm volatile("s_nop 7\n\ts_nop 7" ::: "memory");

    #pragma unroll
    for (int fj = 0; fj < 4; ++fj) {
        const int col = bn + wn * 64 + fj * 16 + (lane & 15);
        #pragma unroll
        for (int fi = 0; fi < 4; ++fi) {
            const int r0 = bm + wm * 64 + fi * 16 + (lane >> 4) * 4;
            #pragma unroll
            for (int j = 0; j < 4; ++j) {
                float v = acc[fi][fj][j] + bias[r0 + j];
                Cb[(size_t)(r0 + j) * N + col] = f2bf(v);
            }
        }
    }
}

// ---------------------------------------------------------------------------
// Fused attn — round-11 verified kernel + T14 prefetch ONLY:
//  * K tile t+1's global loads issued right after WRITE of tile t (latency
//    hides under MFMA + barriers). Same for V in PV.
//  * score-loop barrier-3 removed (redundant: k_s reads precede barrier-2;
//    red is re-written only after next tile's barrier-1).
// Staged values / layout / arithmetic bit-identical to round 11.
// ---------------------------------------------------------------------------
#define ATT_LDS 65280

__global__ __launch_bounds__(512) void attn_topk_fused(
    const float* __restrict__ Qb, const unsigned short* __restrict__ Ks,
    const unsigned short* __restrict__ Vt, float* __restrict__ attn_out,
    float* __restrict__ CTX)
{
    __shared__ __align__(16) char smem[ATT_LDS];
    unsigned short* q_s = (unsigned short*)smem;                   // [3][16][136]
    unsigned short* k_s = (unsigned short*)(smem + 13056);         // [3][64][136]
    float*          red = (float*)smem;                            // [4][16][16]
    unsigned short* wt  = (unsigned short*)(smem + 13056);         // [16][1032]
    unsigned short* vt  = (unsigned short*)(smem + 13056 + 33024); // [128][72]

    const int tid = threadIdx.x;
    const int wv = tid >> 6, lane = tid & 63;
    const int fg = lane >> 4, fc = lane & 15;

    // XCD-chunked bijective remap: 4096 = 8 XCDs x 512
    const int gg = (blockIdx.x & 7) * 512 + ((int)blockIdx.x >> 3);
    const int bh = gg >> 6, qb = gg & 63;
    const int b = bh >> 4, h = bh & 15;
    const int q0 = qb * 16;

    const float* Qg = Qb + (size_t)(b * SS + q0) * DD + h * DKK;
    const unsigned short* Ksg = Ks + (size_t)bh * SS * DKK;
    const unsigned short* Vtg = Vt + (size_t)(h * DKK) * MROWS + b * SS;
    float* aob = attn_out + (size_t)(bh * SS + q0) * SS;

    // ---- issue K tile-0 prefetch before Q staging (overlaps) ----
    su8 rk[6];
    #pragma unroll
    for (int pu = 0; pu < 6; ++pu) {
        const int p = pu >> 1;
        const int rem = tid + 512 * (pu & 1);
        const int row = rem >> 4, c8 = rem & 15;
        rk[pu] = *(const su8*)(Ksg + p * KPLANE +
                               (size_t)row * DKK + c8 * 8);
    }

    // ---- stage Q splits (once): 512 units = 16 rows x 32 c4 ----
    {
        int row = tid >> 5, c4 = tid & 31;
        float4 v = *(const float4*)(Qg + (size_t)row * DD + c4 * 4);
        int off = row * 136 + c4 * 4;
        su4 p1, p2, p3; split4(v, p1, p2, p3);
        *(su4*)&q_s[off] = p1;
        *(su4*)&q_s[2176 + off] = p2;
        *(su4*)&q_s[4352 + off] = p3;
    }
    __syncthreads();

    // ---- persistent A-frags: af[split][ktile-of-my-dhalf] ----
    const int kt0 = (wv >> 2) * 2;   // ktile base: 0 (d 0..63) or 2 (d 64..127)
    su8 af[3][2];
    #pragma unroll
    for (int p = 0; p < 3; ++p)
        #pragma unroll
        for (int kk = 0; kk < 2; ++kk)
            af[p][kk] = *(const su8*)&q_s[p * 2176 + fc * 136 +
                            ((kt0 + kk) * 4 + fg) * 8];

    // ---- scores over 16 key-tiles of 64 (prefetched pipeline) ----
    for (int t = 0; t < 16; ++t) {
        // write prefetched tile t (k_s reads of t-1 done before barrier-2(t-1))
        #pragma unroll
        for (int pu = 0; pu < 6; ++pu) {
            const int p = pu >> 1;
            const int rem = tid + 512 * (pu & 1);
            const int row = rem >> 4, c8 = rem & 15;
            *(su8*)&k_s[p * 8704 + row * 136 + c8 * 8] = rk[pu];
        }
        // issue loads for tile t+1 (fly during MFMA + barriers)
        if (t < 15) {
            #pragma unroll
            for (int pu = 0; pu < 6; ++pu) {
                const int p = pu >> 1;
                const int rem = tid + 512 * (pu & 1);
                const int row = rem >> 4, c8 = rem & 15;
                rk[pu] = *(const su8*)(Ksg + p * KPLANE +
                            (size_t)((t + 1) * 64 + row) * DKK + c8 * 8);
            }
        }
        __syncthreads();   // k_s tile t visible

        const int krow = (wv & 3) * 16 + fc;
        su8 bf[3][2];
        #pragma unroll
        for (int p = 0; p < 3; ++p)
            #pragma unroll
            for (int kk = 0; kk < 2; ++kk)
                bf[p][kk] = *(const su8*)&k_s[p * 8704 + krow * 136 +
                                ((kt0 + kk) * 4 + fg) * 8];

        f32x4 acc = {0.f, 0.f, 0.f, 0.f};
        // passes small->large: (q3,k1),(q1,k3),(q2,k2),(q2,k1),(q1,k2),(q1,k1)
        constexpr int PI[6] = {2, 0, 1, 1, 0, 0};
        constexpr int PJ[6] = {0, 2, 1, 0, 1, 0};
        #pragma unroll
        for (int p = 0; p < 6; ++p)
            #pragma unroll
            for (int kk = 0; kk < 2; ++kk)
                asm volatile("v_mfma_f32_16x16x32_bf16 %0, %1, %2, %0"
                             : "+v"(acc) : "v"(af[PI[p]][kk]), "v"(bf[PJ[p]][kk]));
        asm volatile("s_nop 7\n\ts_nop 7" ::: "memory");

        if (kt0 == 2) {
            #pragma unroll
            for (int j = 0; j < 4; ++j)
                red[(wv & 3) * 256 + (4 * fg + j) * 16 + fc] = acc[j];
        }
        __syncthreads();   // red visible; k_s reads done -> restage OK next iter
        if (kt0 == 0) {
            #pragma unroll
            for (int j = 0; j < 4; ++j) {
                float s = (acc[j] + red[(wv & 3) * 256 + (4 * fg + j) * 16 + fc]) * SCALE;
                aob[(size_t)(4 * fg + j) * SS + t * 64 + (wv & 3) * 16 + fc] = s;
            }
        }
        // barrier-3 removed: red re-written only after next iter's barrier-1;
        // k_s re-written at next iter top, after this barrier.
    }
    __syncthreads();  // all scores visible within block

    // ---- selection + softmax params (verified ballot bit-descent), 2 rows ----
    unsigned uv[2][16];
    #pragma unroll
    for (int rr = 0; rr < 2; ++rr) {
        const float* aor = aob + (size_t)(2 * wv + rr) * SS;
        #pragma unroll
        for (int t = 0; t < 16; ++t)
            uv[rr][t] = f2u_ord(aor[t * 64 + lane]);
    }
    unsigned pref[2]; int ecnt[2]; float mrow[2], invz[2], tvexp[2];
    #pragma unroll
    for (int rr = 0; rr < 2; ++rr) {
        unsigned p = 0;
        for (int bit = 31; bit >= 0; --bit) {
            unsigned cand = p | (1u << bit);
            int cnt = 0;
            #pragma unroll
            for (int t = 0; t < 16; ++t)
                cnt += __popcll(__ballot(uv[rr][t] >= cand));
            if (cnt >= KKTOP) p = cand;
        }
        pref[rr] = p;
        int g = 0;
        #pragma unroll
        for (int t = 0; t < 16; ++t)
            g += __popcll(__ballot(uv[rr][t] > p));
        ecnt[rr] = KKTOP - g;

        unsigned um = 0;
        #pragma unroll
        for (int t = 0; t < 16; ++t) um = um > uv[rr][t] ? um : uv[rr][t];
        #pragma unroll
        for (int o = 32; o > 0; o >>= 1) {
            unsigned tv2 = __shfl_down(um, o);
            um = um > tv2 ? um : tv2;
        }
        um = __shfl(um, 0);
        const float m = u2f_ord(um);

        float se = 0.f;
        #pragma unroll
        for (int t = 0; t < 16; ++t)
            if (uv[rr][t] > p) se += expf(u2f_ord(uv[rr][t]) - m);
        #pragma unroll
        for (int o = 32; o > 0; o >>= 1) se += __shfl_down(se, o);
        se = __shfl(se, 0);

        mrow[rr] = m;
        tvexp[rr] = expf(u2f_ord(p) - m);
        invz[rr] = 1.0f / (se + (float)ecnt[rr] * tvexp[rr]);
    }

    // ---- weights: attn_out final + wt bf16 (ties in (t,lane) index order) ----
    #pragma unroll
    for (int rr = 0; rr < 2; ++rr) {
        float* aor = aob + (size_t)(2 * wv + rr) * SS;
        unsigned short* wr = wt + (2 * wv + rr) * 1032;
        int tiesbefore = 0;
        #pragma unroll
        for (int t = 0; t < 16; ++t) {
            const unsigned u = uv[rr][t];
            const bool eq = (u == pref[rr]);
            unsigned long long mask = __ballot(eq);
            float w;
            if (u > pref[rr]) {
                w = expf(u2f_ord(u) - mrow[rr]) * invz[rr];
            } else if (eq) {
                int rank = tiesbefore + __popcll(mask & ((1ull << lane) - 1ull));
                w = (rank < ecnt[rr]) ? tvexp[rr] * invz[rr] : 0.f;
            } else {
                w = 0.f;
            }
            aor[t * 64 + lane] = w;
            wr[t * 64 + lane] = f2bf(w);
            tiesbefore += __popcll(mask);
        }
    }

    // ---- PV: ctx[16][128] = W[16][1024] @ V[1024][128], prefetched ----
    f32x4 pacc = {0.f, 0.f, 0.f, 0.f};
    const int pvd = wv * 16 + fc;        // this lane's d column
    su8 rv[2];
    #pragma unroll
    for (int u = 0; u < 2; ++u) {
        int rem = tid + 512 * u;
        int d = rem >> 3, kc = rem & 7;
        rv[u] = *(const su8*)(Vtg + (size_t)d * MROWS + kc * 8);
    }
    for (int t = 0; t < 16; ++t) {
        __syncthreads();   // wt complete (t=0) / prev vt MFMA reads done
        #pragma unroll
        for (int u = 0; u < 2; ++u) {
            int rem = tid + 512 * u;
            int d = rem >> 3, kc = rem & 7;
            *(su8*)&vt[d * 72 + kc * 8] = rv[u];
        }
        if (t < 15) {
            #pragma unroll
            for (int u = 0; u < 2; ++u) {
                int rem = tid + 512 * u;
                int d = rem >> 3, kc = rem & 7;
                rv[u] = *(const su8*)(Vtg + (size_t)d * MROWS +
                                      (t + 1) * 64 + kc * 8);
            }
        }
        __syncthreads();
        #pragma unroll
        for (int kk = 0; kk < 2; ++kk) {
            su8 aw = *(const su8*)&wt[fc * 1032 + t * 64 + (kk * 4 + fg) * 8];
            su8 bv2 = *(const su8*)&vt[pvd * 72 + (kk * 4 + fg) * 8];
            asm volatile("v_mfma_f32_16x16x32_bf16 %0, %1, %2, %0"
                         : "+v"(pacc) : "v"(aw), "v"(bv2));
        }
    }
    asm volatile("s_nop 7\n\ts_nop 7" ::: "memory");

    #pragma unroll
    for (int j = 0; j < 4; ++j)
        CTX[(size_t)(b * SS + q0 + 4 * fg + j) * DD + h * DKK + pvd] = pacc[j];
}

// ---------------------------------------------------------------------------
extern "C" void kernel_launch(void* const* d_in, const int* in_sizes, int n_in,
                              void* d_out, int out_size, void* d_ws, size_t ws_size,
                              hipStream_t stream)
{
    const float* x  = (const float*)d_in[0];
    const float* Wq = (const float*)d_in[1];
    const float* bq = (const float*)d_in[2];
    const float* Wk = (const float*)d_in[3];
    const float* bk = (const float*)d_in[4];
    const float* Wv = (const float*)d_in[5];
    const float* bv = (const float*)d_in[6];
    const float* Wo = (const float*)d_in[7];
    const float* bo = (const float*)d_in[8];

    float* out      = (float*)d_out;                       // [4,1024,2048]
    float* attn_out = (float*)d_out + (size_t)MROWS * DD;  // [4,16,1024,1024]

    float* ws = (float*)d_ws;
    const size_t PLANE = (size_t)MROWS * DD;   // 8,388,608
    // ws carve (134.2 MB, identical to round-9/11/12):
    float* Qb = ws;
    unsigned short* Ksp = (unsigned short*)(ws + PLANE);
    float* CTX = ws + PLANE + PLANE * 3 / 2;
    unsigned short* Vtp = (unsigned short*)(ws + PLANE + PLANE * 3 / 2 + PLANE);

    dim3 gb(MROWS / TM, DD / TN);   // (32,16)
    gemm_nt_3p<<<gb, 256, 0, stream>>>(x, Wq, bq, Qb, MROWS, DD, DD);
    gemm_nt_3p_ksplit<<<gb, 256, 0, stream>>>(x, Wk, bk, Ksp, MROWS, DD, DD);
    gemm_nt_bf16_tv<<<dim3(DD / TM, MROWS / TN), 256, 0, stream>>>(
        Wv, x, bv, Vtp, DD, MROWS, DD);

    attn_topk_fused<<<dim3(BB * HH * (SS / 16)), 512, 0, stream>>>(
        Qb, Ksp, Vtp, attn_out, CTX);

    gemm_nt_bf16<<<gb, 256, 0, stream>>>(CTX, Wo, bo, out, MROWS, DD, DD);
}